// Round 10
// baseline (148.099 us; speedup 1.0000x reference)
//
#include <hip/hip_runtime.h>
#include <hip/hip_bf16.h>

// ---------------------------------------------------------------------------
// SelfAttention2d, fully-MFMA pipeline, fragment-major memory layouts.
// MFMA 16x16x32 bf16: A[m=il][k=q*8+j], B[col=il][k=q*8+j], C[row=q*4+r][col=il]
//
// R10: (a) conv v6 — R7's 2-blocks/CU x 256 blocks only occupied 128 CUs.
// Double-buffer W/X LDS tiles (137KB -> 1 block/CU -> ALL 256 CUs), stage
// kc+1 async during kc's compute, ONE barrier per kc. Per-CU staging bytes
// halve and overlap compute. (b) attn — lanes q>=2 feed A-values into k>=16
// where B(=qa) is exactly zero; their K loads were pure waste. Exec-mask the
// K loads (if q<2) with a one-time zero init (keeps masked lanes finite):
// K L2 traffic halves.
//
// Attention computes S TRANSPOSED (A=K, B=Q) so each lane holds
// S[m=m0+il][n=nb+q*4+r]:  pw lookups become ny-invariant registers, ph is one
// read/ny, and P needs only an 8B LDS write + b128 read to become the PV
// A-operand (full K=32).
//
// Layouts:
//   XC   [b][kc 0..7][y 0..33][x 0..33][ci 32]  zero-padded image, bf16
//   WB3  [coG6][nt4][kc8][tap9][lane64][8]      w_out frag-major
//   WK2  [coG6][nt4][kc8][lane64][8]            w_kqv frag-major
//   WA2  [coG2][nt4][kc4][lane64][8]            w_attn frag-major
//   VT   [bh][ny32][d16][ci 32]                 V^T frag-major
//   artX [b][kc4][pp1024][ci32]                 attn out, frag-major
//
// ws (ushort units, 7,262,208 B <= proven-safe 8,192,000):
//   WB3 0 / WK2 884736 / WA2 983040 / KRWB 999424 / KRHB 1000448 /
//   XC 1001472 (2,367,488) / ART2 3368960 (b=6,7 slots)
// d_out scratch (ushort): KS 0 / QS 1048576 / VT 2097152 / ART1 7340032 (b0..5)
// Order: prep(+ring+xt) -> kqv -> attn -> attn_out -> conv
// ---------------------------------------------------------------------------

typedef short v8s __attribute__((ext_vector_type(8)));
typedef float v4f __attribute__((ext_vector_type(4)));

#define WB2_US   0u
#define WK2_US   884736u
#define WA2_US   983040u
#define KRWB_US  999424u
#define KRHB_US  1000448u
#define XC_US    1001472u
#define ART2_US  3368960u

#define KS_US    0u
#define QS_US    1048576u
#define VTS_US   2097152u
#define ART1_US  7340032u

#define QSCALE 0.360673760f   // 0.25 * log2(e)
#define SHIFT2 17.3123405f    // 12 * log2(e)

__device__ __forceinline__ unsigned short f2bs(float f) {
  __hip_bfloat16 h = __float2bfloat16(f);
  return *reinterpret_cast<unsigned short*>(&h);
}

// ---------------------------------------------------------------------------
// Fused: [0,3912) weight/KR transform; [3912,4044) XC pad-ring zero;
// [4044,4556) xt (x fp32 -> XC interior bf16).
__global__ __launch_bounds__(256) void prep_kernel(
    const float* __restrict__ w_out, const float* __restrict__ w_kqv,
    const float* __restrict__ w_attn, const float* __restrict__ krw,
    const float* __restrict__ krh, const float* __restrict__ x,
    unsigned short* __restrict__ ws) {
  __shared__ float t[64][65];
  int bx = blockIdx.x;
  if (bx < 3912) {
    int i = bx * 256 + threadIdx.x;
    if (i < 884736) {              // WB3[coG][nt][kc][tap][lane][8]
      int j = i & 7, l = (i >> 3) & 63;
      int r = i >> 9;              // fragment chunk index [coG][nt][kc][tap]
      int tap = r % 9; int r2 = r / 9;
      int kc = r2 & 7, nt = (r2 >> 3) & 3, coG = r2 >> 5;
      int co = coG * 64 + nt * 16 + (l & 15);
      int ci = kc * 32 + (l >> 4) * 8 + j;
      ws[WB2_US + i] = f2bs(w_out[(size_t)co * 2304 + ci * 9 + tap]);
    } else if (i < 983040) {       // WK2[coG][nt][kc][lane][8]
      int o = i - 884736;
      int j = o & 7, l = (o >> 3) & 63, kc = (o >> 9) & 7, nt = (o >> 12) & 3;
      int coG = o >> 14;
      int co = coG * 64 + nt * 16 + (l & 15);
      int ci = kc * 32 + (l >> 4) * 8 + j;
      ws[WK2_US + o] = f2bs(w_kqv[co * 256 + ci]);
    } else if (i < 999424) {       // WA2[coG][nt][kc][lane][8]
      int o = i - 983040;
      int j = o & 7, l = (o >> 3) & 63, kc = (o >> 9) & 3, nt = (o >> 11) & 3;
      int coG = o >> 13;
      int co = coG * 64 + nt * 16 + (l & 15);
      int ci = kc * 32 + (l >> 4) * 8 + j;
      ws[WA2_US + o] = f2bs(w_attn[co * 128 + ci]);
    } else if (i < 1000448) {      // krw bf16 [64][16], row 63 zero
      int j = i - 999424; int c = j >> 4, d = j & 15;
      ws[KRWB_US + j] = (c < 63) ? f2bs(krw[c * 16 + d]) : (unsigned short)0;
    } else if (i < 1001472) {
      int j = i - 1000448; int c = j >> 4, d = j & 15;
      ws[KRHB_US + j] = (c < 63) ? f2bs(krh[c * 16 + d]) : (unsigned short)0;
    }
  } else if (bx < 4044) {
    // XC pad ring: 64 slices x 132 pixels x 4 uint4. 33792 uint4 total.
    int g = (bx - 3912) * 256 + threadIdx.x;
    int slice = g / 528, rem = g % 528;
    int pix = rem >> 2, d = rem & 3;
    int y, xx;
    if (pix < 34)       { y = 0;        xx = pix; }
    else if (pix < 68)  { y = 33;       xx = pix - 34; }
    else if (pix < 100) { y = pix - 67; xx = 0; }
    else                { y = pix - 99; xx = 33; }
    uint4 z = {0u, 0u, 0u, 0u};
    ((uint4*)(ws + XC_US))[(slice * 1156 + y * 34 + xx) * 4 + d] = z;
  } else {
    // xt: x [b][ci][pos] fp32 -> XC[b][ci>>5][y+1][x+1][ci&31] bf16.
    int blk = bx - 4044;
    int tid = threadIdx.x; int pl = tid & 63, cg = tid >> 6;
    int pos0 = (blk & 15) * 64, ci0 = ((blk >> 4) & 3) * 64, b = blk >> 6;
    unsigned short* xc = ws + XC_US;
    const float* xb = x + ((size_t)(b * 256 + ci0)) * 1024 + pos0;
#pragma unroll
    for (int i = 0; i < 16; ++i) {
      int ci_l = cg * 16 + i;
      t[ci_l][pl] = xb[(size_t)ci_l * 1024 + pl];
    }
    __syncthreads();
#pragma unroll
    for (int i = 0; i < 16; ++i) {
      int pos_l = cg * 16 + i;
      int pos = pos0 + pos_l;
      int y = (pos >> 5) + 1, xx = (pos & 31) + 1;
      int ci = ci0 + pl;
      xc[((size_t)((b * 8 + (ci >> 5)) * 34 + y) * 34 + xx) * 32 + (ci & 31)] =
          f2bs(t[pl][pos_l]);
    }
  }
}

// ---------------------------------------------------------------------------
// kqv GEMM: A-frags from XC (tap 1,1; contiguous 1KB loads), B from WK2.
// 4 waves/block; wave (mh,nh) owns the 2x2 quadrant (mt=mh*2+mi, nt=nh*2+ni).
// Full kc unroll + 4-slot depth-3 rolling prefetch of A/B fragments.
// 1D grid 768, b = bx&7 pins batch to XCD (XC slice + WK2 L2-resident).
__global__ __launch_bounds__(256) void kqv_mfma(
    const unsigned short* __restrict__ xc, const unsigned short* __restrict__ wk2,
    const float* __restrict__ bkqv, unsigned short* __restrict__ dq) {
  int tid = threadIdx.x;
  int lane = tid & 63; int il = lane & 15, q = lane >> 4;
  int wv = tid >> 6; int mh = wv >> 1, nh = wv & 1;
  int bx = blockIdx.x;
  int b = bx & 7, pt = (bx >> 3) & 15, coG = bx >> 7;
  int pos0 = pt * 64;
  int row0 = pos0 >> 5;
  v4f acc[2][2];
#pragma unroll
  for (int mi = 0; mi < 2; ++mi)
#pragma unroll
    for (int ni = 0; ni < 2; ++ni) acc[mi][ni] = (v4f){0.f, 0.f, 0.f, 0.f};

  int pix[2];
#pragma unroll
  for (int mi = 0; mi < 2; ++mi)
    pix[mi] = (row0 + mh + 1) * 34 + (mi * 16 + il + 1);
  const unsigned short* bt = wk2 + (size_t)coG * 16384 + lane * 8;
  const unsigned short* at = xc + (size_t)(b * 8) * 36992 + q * 8;

  v8s afS[4][2], bfS[4][2];
  // prologue: preload kc = 0..2 into slots 0..2
#pragma unroll
  for (int p = 0; p < 3; ++p) {
#pragma unroll
    for (int ni = 0; ni < 2; ++ni)
      bfS[p][ni] = *(const v8s*)(bt + ((nh * 2 + ni) * 8 + p) * 512);
#pragma unroll
    for (int mi = 0; mi < 2; ++mi)
      afS[p][mi] = *(const v8s*)(at + (size_t)p * 36992 + pix[mi] * 32);
  }

#pragma unroll
  for (int kc = 0; kc < 8; ++kc) {
    if (kc + 3 < 8) {
      int kn = kc + 3, s = kn & 3;
#pragma unroll
      for (int ni = 0; ni < 2; ++ni)
        bfS[s][ni] = *(const v8s*)(bt + ((nh * 2 + ni) * 8 + kn) * 512);
#pragma unroll
      for (int mi = 0; mi < 2; ++mi)
        afS[s][mi] = *(const v8s*)(at + (size_t)kn * 36992 + pix[mi] * 32);
    }
    int cs = kc & 3;
#pragma unroll
    for (int mi = 0; mi < 2; ++mi)
#pragma unroll
      for (int ni = 0; ni < 2; ++ni)
        acc[mi][ni] = __builtin_amdgcn_mfma_f32_16x16x32_bf16(
            afS[cs][mi], bfS[cs][ni], acc[mi][ni], 0, 0, 0);
  }
  int co0 = coG * 64;
#pragma unroll
  for (int ni = 0; ni < 2; ++ni) {
    int nt = nh * 2 + ni;
    int cob = co0 + nt * 16;
    int co = cob + il;
    float bias = bkqv[co];
    int cls = cob >> 7;                  // 0:k 1:q 2:v (uniform per nt)
    int h = (cob >> 4) & 7;
    size_t bh = (size_t)(b * 8 + h);
#pragma unroll
    for (int mi = 0; mi < 2; ++mi) {
      int mt = mh * 2 + mi;
      int pos = pos0 + mt * 16 + q * 4;
      v4f a = acc[mi][ni];
#pragma unroll
      for (int r = 0; r < 4; ++r) {
        float v = a[r] + bias;
        int p = pos + r;
        if (cls == 0)      dq[KS_US + bh * 16384 + p * 16 + il] = f2bs(v);
        else if (cls == 1) dq[QS_US + bh * 16384 + p * 16 + il] = f2bs(v * QSCALE);
        else               dq[VTS_US + bh * 16384 + ((p >> 5) * 16 + il) * 32 + (p & 31)] = f2bs(v);
      }
    }
  }
}

// ---------------------------------------------------------------------------
// MFMA attention, S-transposed formulation. Block 256 = 4 waves; wave owns a
// 16-row m-tile. Lane (q,il) reg r holds S[m0+il][nb+q*4+r].
// Depth-1 register prefetch of next-ny K/V. bh on blockIdx.x (XCD = h, K/V
// L2-resident per XCD). R10: K loads exec-masked to q<2 (q>=2 lanes feed
// k>=16 where B=qa is zero); masked lanes zero-initialized once (finite).
__global__ __launch_bounds__(256) void attn_mfma(
    unsigned short* __restrict__ dq, const unsigned short* __restrict__ krwb,
    const unsigned short* __restrict__ krhb, unsigned short* __restrict__ wsart) {
  __shared__ float lds[4][2448];
  int tid = threadIdx.x; int w = tid >> 6, lane = tid & 63;
  int il = lane & 15, q = lane >> 4;
  int bh = blockIdx.x; int b = bh >> 3, h = bh & 7;
  int m0 = blockIdx.y * 64 + w * 16;
  int my = m0 >> 5, mxb = m0 & 31;
  float* pw = lds[w];                       // [16 rows][stride 64]
  float* ph = pw + 1024;                    // [16 rows][stride 68], - SHIFT2
  unsigned short* pl = (unsigned short*)(ph + 1088);  // [16 rows][stride 40] bf16

  const v8s z8 = {0, 0, 0, 0, 0, 0, 0, 0};
  const v4f z4 = {0.f, 0.f, 0.f, 0.f};

  // Q frag: A-layout for table build == B-layout for S^T (same registers).
  // Zeroed for q>=2 (k>=16): this zero makes all A-side masks unnecessary.
  const unsigned short* qrow = dq + QS_US + (size_t)bh * 16384 + (m0 + il) * 16;
  v8s qa = *(const v8s*)(qrow + (q & 1) * 8);
  qa = (q < 2) ? qa : z8;

  // PW / PH tables via MFMA (A=qa zeroed at k>=16; B-side garbage is harmless)
#pragma unroll
  for (int nt = 0; nt < 4; ++nt) {
    int c = nt * 16 + il;
    v8s bw = *(const v8s*)(krwb + c * 16 + (q & 1) * 8);
    v8s bhh = *(const v8s*)(krhb + c * 16 + (q & 1) * 8);
    v4f pwc = __builtin_amdgcn_mfma_f32_16x16x32_bf16(qa, bw, z4, 0, 0, 0);
    v4f phc = __builtin_amdgcn_mfma_f32_16x16x32_bf16(qa, bhh, z4, 0, 0, 0);
#pragma unroll
    for (int r = 0; r < 4; ++r) {
      pw[(q * 4 + r) * 64 + c] = pwc[r];
      ph[(q * 4 + r) * 68 + c] = phc[r] - SHIFT2;
    }
  }

  // pw lookups are ny-invariant per lane in the transposed scheme: hoist.
  float pwv[2][4];
#pragma unroll
  for (int nt2 = 0; nt2 < 2; ++nt2)
#pragma unroll
    for (int r = 0; r < 4; ++r)
      pwv[nt2][r] = pw[il * 64 + (nt2 * 16 + q * 4 + r) - mxb - il + 31];

  v4f oacc = z4;
  float sacc = 0.f;
  const unsigned short* kbase = dq + KS_US + (size_t)bh * 16384;
  const unsigned short* vbase = dq + VTS_US + (size_t)bh * 16384;

  // depth-1 prefetch of ny=0 K/V; K loads masked to q<2 (zero-init keeps
  // q>=2 lanes finite; their products are multiplied by qa's zeros).
  v8s kb0 = z8, kb1 = z8;
  if (q < 2) {
    kb0 = *(const v8s*)(kbase + (il) * 16 + q * 8);
    kb1 = *(const v8s*)(kbase + (16 + il) * 16 + q * 8);
  }
  v8s vb0 = *(const v8s*)(vbase + (il) * 32 + q * 8);

  for (int ny = 0; ny < 32; ++ny) {
    v8s kc0 = kb0;
    v8s kc1 = kb1;
    v8s vcur = vb0;
    if (ny < 31) {   // issue next-ny loads; land under softmax + PV below
      if (q < 2) {
        kb0 = *(const v8s*)(kbase + ((ny + 1) * 32 + il) * 16 + q * 8);
        kb1 = *(const v8s*)(kbase + ((ny + 1) * 32 + 16 + il) * 16 + q * 8);
      }
      vb0 = *(const v8s*)(vbase + ((ny + 1) * 16 + il) * 32 + q * 8);
    }
    float phv = ph[il * 68 + (ny - my + 31)];
    v4f s[2];
    s[0] = __builtin_amdgcn_mfma_f32_16x16x32_bf16(kc0, qa, z4, 0, 0, 0);
    s[1] = __builtin_amdgcn_mfma_f32_16x16x32_bf16(kc1, qa, z4, 0, 0, 0);
#pragma unroll
    for (int nt2 = 0; nt2 < 2; ++nt2) {
      float p[4];
#pragma unroll
      for (int r = 0; r < 4; ++r) {
        float t = s[nt2][r] + pwv[nt2][r] + phv;
        p[r] = exp2f(t);
        sacc += p[r];
      }
      uint2 pk;
      pk.x = (unsigned)f2bs(p[0]) | ((unsigned)f2bs(p[1]) << 16);
      pk.y = (unsigned)f2bs(p[2]) | ((unsigned)f2bs(p[3]) << 16);
      *(uint2*)(pl + il * 40 + nt2 * 16 + q * 4) = pk;
    }
    v8s pf = *(const v8s*)(pl + il * 40 + q * 8);
    oacc = __builtin_amdgcn_mfma_f32_16x16x32_bf16(pf, vcur, oacc, 0, 0, 0);
  }

  // row sums: lane holds partial for row il; combine quads, then fetch per-r.
  sacc += __shfl_xor(sacc, 16);
  sacc += __shfl_xor(sacc, 32);

  unsigned short* abase = (b < 6) ? (dq + ART1_US + (size_t)b * 131072)
                                  : (wsart + (size_t)(b - 6) * 131072);
#pragma unroll
  for (int r = 0; r < 4; ++r) {
    float sr = __shfl(sacc, q * 4 + r);       // full sum for row q*4+r
    int m = m0 + q * 4 + r;
    int c = h * 16 + (m >> 6);                // ci of art
    int pp = (m & 63) * 16 + il;              // pos' of art
    abase[((c >> 5) * 1024 + pp) * 32 + (c & 31)] = f2bs(oacc[r] / sr);
  }
}

// ---------------------------------------------------------------------------
// attn_out GEMM: A from artX (contiguous), B from WA2 (frag-major).
// 4 waves/block; wave (mh,nh) owns the 2x2 quadrant.
// 1D grid 256, b = bx&7 pins batch to XCD (art slice L2-resident).
__global__ __launch_bounds__(256) void attn_out_mfma(
    const unsigned short* __restrict__ dq, const unsigned short* __restrict__ wsart,
    const unsigned short* __restrict__ wa2, const float* __restrict__ ba,
    float* __restrict__ out) {
  int tid = threadIdx.x;
  int lane = tid & 63; int il = lane & 15, q = lane >> 4;
  int wv = tid >> 6; int mh = wv >> 1, nh = wv & 1;
  int bx = blockIdx.x;
  int b = bx & 7, pt = (bx >> 3) & 15, coG = bx >> 7;
  int pp0 = pt * 64;
  const unsigned short* ab = (b < 6) ? (dq + ART1_US + (size_t)b * 131072)
                                     : (wsart + (size_t)(b - 6) * 131072);
  const unsigned short* bt = wa2 + (size_t)coG * 8192 + lane * 8;
  v4f acc[2][2];
#pragma unroll
  for (int mi = 0; mi < 2; ++mi)
#pragma unroll
    for (int ni = 0; ni < 2; ++ni) acc[mi][ni] = (v4f){0.f, 0.f, 0.f, 0.f};
#pragma unroll
  for (int kc = 0; kc < 4; ++kc) {
    v8s af[2], bf[2];
#pragma unroll
    for (int ni = 0; ni < 2; ++ni)
      bf[ni] = *(const v8s*)(bt + ((nh * 2 + ni) * 4 + kc) * 512);
#pragma unroll
    for (int mi = 0; mi < 2; ++mi)
      af[mi] = *(const v8s*)(ab + (kc * 1024 + pp0 + (mh * 2 + mi) * 16 + il) * 32 + q * 8);
#pragma unroll
    for (int mi = 0; mi < 2; ++mi)
#pragma unroll
      for (int ni = 0; ni < 2; ++ni)
        acc[mi][ni] = __builtin_amdgcn_mfma_f32_16x16x32_bf16(
            af[mi], bf[ni], acc[mi][ni], 0, 0, 0);
  }
  int co0 = coG * 64;
#pragma unroll
  for (int ni = 0; ni < 2; ++ni) {
    int co = co0 + (nh * 2 + ni) * 16 + il;
    float bias = ba[co];
#pragma unroll
    for (int mi = 0; mi < 2; ++mi) {
      int mt = mh * 2 + mi;
      v4f a = acc[mi][ni];
      float4 v; v.x = a[0] + bias; v.y = a[1] + bias;
      v.z = a[2] + bias; v.w = a[3] + bias;
      *(float4*)(out + ((size_t)(b * 512 + 384 + co)) * 1024 + pp0 + mt * 16 + q * 4) = v;
    }
  }
}

// ---------------------------------------------------------------------------
// conv3x3 via MFMA (R10/v6). Block 512 thr = 8 waves, 128 pos x 96 cout
// (wave = mh(0..3) x nh(0..1), tile 32pos x 48cout, 6 MFMA/tap).
// W tile [6 nfg][9 tap][512us] (54KB) + X tile (13KB) DOUBLE-BUFFERED
// (137KB LDS -> 1 block/CU -> all 256 CUs, was 128). stage(kc+1) issued
// async before computing kc; ONE barrier per kc drains it (loads had the
// whole compute window to land). Grid (64,4): b = bx&7 pins batch to XCD.
__global__ __launch_bounds__(512) void conv_mfma(
    const unsigned short* __restrict__ xc, const unsigned short* __restrict__ wb3,
    const float* __restrict__ bo, float* __restrict__ out) {
  __shared__ unsigned short xlds[2][6656];    // 13 slots x 512 each buf
  __shared__ unsigned short wlds[2][27648];   // 54 slots x 512 each buf
  int tid = threadIdx.x;
  int lane = tid & 63; int il = lane & 15, q = lane >> 4;
  int wv = tid >> 6; int mh = wv >> 1, nh = wv & 1;
  int bx = blockIdx.x, nset = blockIdx.y;
  int b = bx & 7, pt = bx >> 3;             // pt 0..7; b fastest => XCD-pinned
  int pos0 = pt * 128, y0 = pt * 4;
  const unsigned short* xb = xc + ((size_t)(b * 8) * 1156 + y0 * 34) * 32;

  v4f acc[2][3];
#pragma unroll
  for (int mi = 0; mi < 2; ++mi)
#pragma unroll
    for (int j = 0; j < 3; ++j) acc[mi][j] = (v4f){0.f, 0.f, 0.f, 0.f};

  // X: lds chunk c=(row*4+q)*34+x <- global chunk row*136+x*4+q of slice kc.
  auto stageX = [&](int buf, int kc) {
    const unsigned short* src = xb + (size_t)kc * 36992;   // 1156*32
#pragma unroll
    for (int t = 0; t < 2; ++t) {
      int s = wv + t * 8;                   // wave-uniform slot
      if (s < 13) {
        int c = s * 64 + lane;
        int row = c / 136, rem = c % 136;
        int qv = rem / 34, xx = rem % 34;
        const unsigned short* g = src + ((row * 136 + xx * 4 + qv) << 3);
        __builtin_amdgcn_global_load_lds(
            (const __attribute__((address_space(1))) void*)g,
            (__attribute__((address_space(3))) void*)(&xlds[buf][s * 512]),
            16, 0, 0);
      }
    }
  };

  // W: lds [nfg][tap][512] <- WB3[(nset*6+nfg)][kc][tap]; slot s: nfg=s/9,tap=s%9.
  auto stageW = [&](int buf, int kc) {
#pragma unroll
    for (int t = 0; t < 7; ++t) {
      int s = wv + t * 8;                   // wave-uniform slot
      if (s < 54) {
        int nfg = s / 9, tp = s % 9;
        const unsigned short* g = wb3 +
            ((size_t)(((nset * 6 + nfg) * 8 + kc) * 9 + tp) * 512 + lane * 8);
        __builtin_amdgcn_global_load_lds(
            (const __attribute__((address_space(1))) void*)g,
            (__attribute__((address_space(3))) void*)(&wlds[buf][s * 512]),
            16, 0, 0);
      }
    }
  };

  stageX(0, 0);
  stageW(0, 0);
  __syncthreads();

  for (int kc = 0; kc < 8; ++kc) {
    int cur = kc & 1;
    if (kc < 7) {                           // async prefetch of kc+1
      stageX(cur ^ 1, kc + 1);
      stageW(cur ^ 1, kc + 1);
    }
#pragma unroll
    for (int tap = 0; tap < 9; ++tap) {
      int ky = tap / 3, kx = tap % 3;
      v8s af[2], bf[3];
#pragma unroll
      for (int j = 0; j < 3; ++j)
        bf[j] = *(const v8s*)&wlds[cur][((nh * 3 + j) * 9 + tap) * 512 + lane * 8];
#pragma unroll
      for (int mi = 0; mi < 2; ++mi) {
        int mf = mh * 2 + mi;
        af[mi] = *(const v8s*)&xlds[cur][((((mf >> 1) + ky) * 4 + q) * 34 +
                                          ((mf & 1) * 16 + kx + il)) * 8];
      }
#pragma unroll
      for (int mi = 0; mi < 2; ++mi)
#pragma unroll
        for (int j = 0; j < 3; ++j)
          acc[mi][j] = __builtin_amdgcn_mfma_f32_16x16x32_bf16(
              af[mi], bf[j], acc[mi][j], 0, 0, 0);
    }
    __syncthreads();   // all reads of cur done + prefetch into cur^1 drained
  }

  int co0 = nset * 96;
#pragma unroll
  for (int j = 0; j < 3; ++j) {
    int co = co0 + (nh * 3 + j) * 16 + il;
    float bias = bo[co];
#pragma unroll
    for (int mi = 0; mi < 2; ++mi) {
      int mf = mh * 2 + mi;
      v4f a = acc[mi][j];
      float4 v; v.x = a[0] + bias; v.y = a[1] + bias;
      v.z = a[2] + bias; v.w = a[3] + bias;
      *(float4*)(out + ((size_t)(b * 512 + co)) * 1024 +
                 pos0 + mf * 16 + q * 4) = v;
    }
  }
}

// ---------------------------------------------------------------------------
extern "C" void kernel_launch(void* const* d_in, const int* in_sizes, int n_in,
                              void* d_out, int out_size, void* d_ws, size_t ws_size,
                              hipStream_t stream) {
  const float* x      = (const float*)d_in[0];
  const float* b_out  = (const float*)d_in[2];
  const float* b_kqv  = (const float*)d_in[4];
  const float* b_attn = (const float*)d_in[6];
  const float* krw    = (const float*)d_in[7];
  const float* krh    = (const float*)d_in[8];
  unsigned short* ws = (unsigned short*)d_ws;
  float* out = (float*)d_out;
  unsigned short* dq = (unsigned short*)d_out;

  prep_kernel<<<4556, 256, 0, stream>>>(
      (const float*)d_in[1], (const float*)d_in[3], (const float*)d_in[5],
      krw, krh, x, ws);
  kqv_mfma<<<768, 256, 0, stream>>>(
      ws + XC_US, ws + WK2_US, b_kqv, dq);
  attn_mfma<<<dim3(64, 16), 256, 0, stream>>>(
      dq, ws + KRWB_US, ws + KRHB_US, ws + ART2_US);
  attn_out_mfma<<<256, 256, 0, stream>>>(
      dq, ws + ART2_US, ws + WA2_US, b_attn, out);
  conv_mfma<<<dim3(64, 4), 512, 0, stream>>>(
      ws + XC_US, ws + WB2_US, b_out, out);
}

// Round 11
// 144.183 us; speedup vs baseline: 1.0272x; 1.0272x over previous
//
#include <hip/hip_runtime.h>
#include <hip/hip_bf16.h>

// ---------------------------------------------------------------------------
// SelfAttention2d, fully-MFMA pipeline, fragment-major memory layouts.
// MFMA 16x16x32 bf16: A[m=il][k=q*8+j], B[col=il][k=q*8+j], C[row=q*4+r][col=il]
//
// R11: A/B isolation of R10's regression (+3.5us). (a) attn REVERTED to R9
// form — R10's if(q<2) K-load mask saved no L2 traffic (q>=2 lanes re-read
// the same cache lines via (q&1)*8 addressing; L1 dedups) and its divergent
// branch broke the depth-1 prefetch pipeline. (b) conv KEEPS v6 (in-block
// dbuf): mechanism sound — R7 at 1 block/CU (dispatcher spreads blocks
// one-per-CU; occupancy caps are caps, not assignments) had NO staging/
// compute overlap; v6 overlaps them. If total stays ~148, conv v6 is the
// true regressor and gets reverted next.
//
// Attention computes S TRANSPOSED (A=K, B=Q) so each lane holds
// S[m=m0+il][n=nb+q*4+r]:  pw lookups become ny-invariant registers, ph is one
// read/ny, and P needs only an 8B LDS write + b128 read to become the PV
// A-operand (full K=32).
//
// Layouts:
//   XC   [b][kc 0..7][y 0..33][x 0..33][ci 32]  zero-padded image, bf16
//   WB3  [coG6][nt4][kc8][tap9][lane64][8]      w_out frag-major
//   WK2  [coG6][nt4][kc8][lane64][8]            w_kqv frag-major
//   WA2  [coG2][nt4][kc4][lane64][8]            w_attn frag-major
//   VT   [bh][ny32][d16][ci 32]                 V^T frag-major
//   artX [b][kc4][pp1024][ci32]                 attn out, frag-major
//
// ws (ushort units, 7,262,208 B <= proven-safe 8,192,000):
//   WB3 0 / WK2 884736 / WA2 983040 / KRWB 999424 / KRHB 1000448 /
//   XC 1001472 (2,367,488) / ART2 3368960 (b=6,7 slots)
// d_out scratch (ushort): KS 0 / QS 1048576 / VT 2097152 / ART1 7340032 (b0..5)
// Order: prep(+ring+xt) -> kqv -> attn -> attn_out -> conv
// ---------------------------------------------------------------------------

typedef short v8s __attribute__((ext_vector_type(8)));
typedef float v4f __attribute__((ext_vector_type(4)));

#define WB2_US   0u
#define WK2_US   884736u
#define WA2_US   983040u
#define KRWB_US  999424u
#define KRHB_US  1000448u
#define XC_US    1001472u
#define ART2_US  3368960u

#define KS_US    0u
#define QS_US    1048576u
#define VTS_US   2097152u
#define ART1_US  7340032u

#define QSCALE 0.360673760f   // 0.25 * log2(e)
#define SHIFT2 17.3123405f    // 12 * log2(e)

__device__ __forceinline__ unsigned short f2bs(float f) {
  __hip_bfloat16 h = __float2bfloat16(f);
  return *reinterpret_cast<unsigned short*>(&h);
}

// ---------------------------------------------------------------------------
// Fused: [0,3912) weight/KR transform; [3912,4044) XC pad-ring zero;
// [4044,4556) xt (x fp32 -> XC interior bf16).
__global__ __launch_bounds__(256) void prep_kernel(
    const float* __restrict__ w_out, const float* __restrict__ w_kqv,
    const float* __restrict__ w_attn, const float* __restrict__ krw,
    const float* __restrict__ krh, const float* __restrict__ x,
    unsigned short* __restrict__ ws) {
  __shared__ float t[64][65];
  int bx = blockIdx.x;
  if (bx < 3912) {
    int i = bx * 256 + threadIdx.x;
    if (i < 884736) {              // WB3[coG][nt][kc][tap][lane][8]
      int j = i & 7, l = (i >> 3) & 63;
      int r = i >> 9;              // fragment chunk index [coG][nt][kc][tap]
      int tap = r % 9; int r2 = r / 9;
      int kc = r2 & 7, nt = (r2 >> 3) & 3, coG = r2 >> 5;
      int co = coG * 64 + nt * 16 + (l & 15);
      int ci = kc * 32 + (l >> 4) * 8 + j;
      ws[WB2_US + i] = f2bs(w_out[(size_t)co * 2304 + ci * 9 + tap]);
    } else if (i < 983040) {       // WK2[coG][nt][kc][lane][8]
      int o = i - 884736;
      int j = o & 7, l = (o >> 3) & 63, kc = (o >> 9) & 7, nt = (o >> 12) & 3;
      int coG = o >> 14;
      int co = coG * 64 + nt * 16 + (l & 15);
      int ci = kc * 32 + (l >> 4) * 8 + j;
      ws[WK2_US + o] = f2bs(w_kqv[co * 256 + ci]);
    } else if (i < 999424) {       // WA2[coG][nt][kc][lane][8]
      int o = i - 983040;
      int j = o & 7, l = (o >> 3) & 63, kc = (o >> 9) & 3, nt = (o >> 11) & 3;
      int coG = o >> 13;
      int co = coG * 64 + nt * 16 + (l & 15);
      int ci = kc * 32 + (l >> 4) * 8 + j;
      ws[WA2_US + o] = f2bs(w_attn[co * 128 + ci]);
    } else if (i < 1000448) {      // krw bf16 [64][16], row 63 zero
      int j = i - 999424; int c = j >> 4, d = j & 15;
      ws[KRWB_US + j] = (c < 63) ? f2bs(krw[c * 16 + d]) : (unsigned short)0;
    } else if (i < 1001472) {
      int j = i - 1000448; int c = j >> 4, d = j & 15;
      ws[KRHB_US + j] = (c < 63) ? f2bs(krh[c * 16 + d]) : (unsigned short)0;
    }
  } else if (bx < 4044) {
    // XC pad ring: 64 slices x 132 pixels x 4 uint4. 33792 uint4 total.
    int g = (bx - 3912) * 256 + threadIdx.x;
    int slice = g / 528, rem = g % 528;
    int pix = rem >> 2, d = rem & 3;
    int y, xx;
    if (pix < 34)       { y = 0;        xx = pix; }
    else if (pix < 68)  { y = 33;       xx = pix - 34; }
    else if (pix < 100) { y = pix - 67; xx = 0; }
    else                { y = pix - 99; xx = 33; }
    uint4 z = {0u, 0u, 0u, 0u};
    ((uint4*)(ws + XC_US))[(slice * 1156 + y * 34 + xx) * 4 + d] = z;
  } else {
    // xt: x [b][ci][pos] fp32 -> XC[b][ci>>5][y+1][x+1][ci&31] bf16.
    int blk = bx - 4044;
    int tid = threadIdx.x; int pl = tid & 63, cg = tid >> 6;
    int pos0 = (blk & 15) * 64, ci0 = ((blk >> 4) & 3) * 64, b = blk >> 6;
    unsigned short* xc = ws + XC_US;
    const float* xb = x + ((size_t)(b * 256 + ci0)) * 1024 + pos0;
#pragma unroll
    for (int i = 0; i < 16; ++i) {
      int ci_l = cg * 16 + i;
      t[ci_l][pl] = xb[(size_t)ci_l * 1024 + pl];
    }
    __syncthreads();
#pragma unroll
    for (int i = 0; i < 16; ++i) {
      int pos_l = cg * 16 + i;
      int pos = pos0 + pos_l;
      int y = (pos >> 5) + 1, xx = (pos & 31) + 1;
      int ci = ci0 + pl;
      xc[((size_t)((b * 8 + (ci >> 5)) * 34 + y) * 34 + xx) * 32 + (ci & 31)] =
          f2bs(t[pl][pos_l]);
    }
  }
}

// ---------------------------------------------------------------------------
// kqv GEMM: A-frags from XC (tap 1,1; contiguous 1KB loads), B from WK2.
// 4 waves/block; wave (mh,nh) owns the 2x2 quadrant (mt=mh*2+mi, nt=nh*2+ni).
// Full kc unroll + 4-slot depth-3 rolling prefetch of A/B fragments.
// 1D grid 768, b = bx&7 pins batch to XCD (XC slice + WK2 L2-resident).
__global__ __launch_bounds__(256) void kqv_mfma(
    const unsigned short* __restrict__ xc, const unsigned short* __restrict__ wk2,
    const float* __restrict__ bkqv, unsigned short* __restrict__ dq) {
  int tid = threadIdx.x;
  int lane = tid & 63; int il = lane & 15, q = lane >> 4;
  int wv = tid >> 6; int mh = wv >> 1, nh = wv & 1;
  int bx = blockIdx.x;
  int b = bx & 7, pt = (bx >> 3) & 15, coG = bx >> 7;
  int pos0 = pt * 64;
  int row0 = pos0 >> 5;
  v4f acc[2][2];
#pragma unroll
  for (int mi = 0; mi < 2; ++mi)
#pragma unroll
    for (int ni = 0; ni < 2; ++ni) acc[mi][ni] = (v4f){0.f, 0.f, 0.f, 0.f};

  int pix[2];
#pragma unroll
  for (int mi = 0; mi < 2; ++mi)
    pix[mi] = (row0 + mh + 1) * 34 + (mi * 16 + il + 1);
  const unsigned short* bt = wk2 + (size_t)coG * 16384 + lane * 8;
  const unsigned short* at = xc + (size_t)(b * 8) * 36992 + q * 8;

  v8s afS[4][2], bfS[4][2];
  // prologue: preload kc = 0..2 into slots 0..2
#pragma unroll
  for (int p = 0; p < 3; ++p) {
#pragma unroll
    for (int ni = 0; ni < 2; ++ni)
      bfS[p][ni] = *(const v8s*)(bt + ((nh * 2 + ni) * 8 + p) * 512);
#pragma unroll
    for (int mi = 0; mi < 2; ++mi)
      afS[p][mi] = *(const v8s*)(at + (size_t)p * 36992 + pix[mi] * 32);
  }

#pragma unroll
  for (int kc = 0; kc < 8; ++kc) {
    if (kc + 3 < 8) {
      int kn = kc + 3, s = kn & 3;
#pragma unroll
      for (int ni = 0; ni < 2; ++ni)
        bfS[s][ni] = *(const v8s*)(bt + ((nh * 2 + ni) * 8 + kn) * 512);
#pragma unroll
      for (int mi = 0; mi < 2; ++mi)
        afS[s][mi] = *(const v8s*)(at + (size_t)kn * 36992 + pix[mi] * 32);
    }
    int cs = kc & 3;
#pragma unroll
    for (int mi = 0; mi < 2; ++mi)
#pragma unroll
      for (int ni = 0; ni < 2; ++ni)
        acc[mi][ni] = __builtin_amdgcn_mfma_f32_16x16x32_bf16(
            afS[cs][mi], bfS[cs][ni], acc[mi][ni], 0, 0, 0);
  }
  int co0 = coG * 64;
#pragma unroll
  for (int ni = 0; ni < 2; ++ni) {
    int nt = nh * 2 + ni;
    int cob = co0 + nt * 16;
    int co = cob + il;
    float bias = bkqv[co];
    int cls = cob >> 7;                  // 0:k 1:q 2:v (uniform per nt)
    int h = (cob >> 4) & 7;
    size_t bh = (size_t)(b * 8 + h);
#pragma unroll
    for (int mi = 0; mi < 2; ++mi) {
      int mt = mh * 2 + mi;
      int pos = pos0 + mt * 16 + q * 4;
      v4f a = acc[mi][ni];
#pragma unroll
      for (int r = 0; r < 4; ++r) {
        float v = a[r] + bias;
        int p = pos + r;
        if (cls == 0)      dq[KS_US + bh * 16384 + p * 16 + il] = f2bs(v);
        else if (cls == 1) dq[QS_US + bh * 16384 + p * 16 + il] = f2bs(v * QSCALE);
        else               dq[VTS_US + bh * 16384 + ((p >> 5) * 16 + il) * 32 + (p & 31)] = f2bs(v);
      }
    }
  }
}

// ---------------------------------------------------------------------------
// MFMA attention, S-transposed formulation. Block 256 = 4 waves; wave owns a
// 16-row m-tile. Lane (q,il) reg r holds S[m0+il][nb+q*4+r].
// Depth-1 register prefetch of next-ny K/V. bh on blockIdx.x (XCD = h, K/V
// L2-resident per XCD). R11: reverted to R9's branchless loads — (q&1)*8
// addressing lets q>=2 lanes re-read q0/q1's cache lines (L1-dedup'd, free).
__global__ __launch_bounds__(256) void attn_mfma(
    unsigned short* __restrict__ dq, const unsigned short* __restrict__ krwb,
    const unsigned short* __restrict__ krhb, unsigned short* __restrict__ wsart) {
  __shared__ float lds[4][2448];
  int tid = threadIdx.x; int w = tid >> 6, lane = tid & 63;
  int il = lane & 15, q = lane >> 4;
  int bh = blockIdx.x; int b = bh >> 3, h = bh & 7;
  int m0 = blockIdx.y * 64 + w * 16;
  int my = m0 >> 5, mxb = m0 & 31;
  float* pw = lds[w];                       // [16 rows][stride 64]
  float* ph = pw + 1024;                    // [16 rows][stride 68], - SHIFT2
  unsigned short* pl = (unsigned short*)(ph + 1088);  // [16 rows][stride 40] bf16

  const v8s z8 = {0, 0, 0, 0, 0, 0, 0, 0};
  const v4f z4 = {0.f, 0.f, 0.f, 0.f};

  // Q frag: A-layout for table build == B-layout for S^T (same registers).
  // Zeroed for q>=2 (k>=16): this zero makes all A-side masks unnecessary.
  const unsigned short* qrow = dq + QS_US + (size_t)bh * 16384 + (m0 + il) * 16;
  v8s qa = *(const v8s*)(qrow + (q & 1) * 8);
  qa = (q < 2) ? qa : z8;

  // PW / PH tables via MFMA (A=qa zeroed at k>=16; B-side garbage is harmless)
#pragma unroll
  for (int nt = 0; nt < 4; ++nt) {
    int c = nt * 16 + il;
    v8s bw = *(const v8s*)(krwb + c * 16 + (q & 1) * 8);
    v8s bhh = *(const v8s*)(krhb + c * 16 + (q & 1) * 8);
    v4f pwc = __builtin_amdgcn_mfma_f32_16x16x32_bf16(qa, bw, z4, 0, 0, 0);
    v4f phc = __builtin_amdgcn_mfma_f32_16x16x32_bf16(qa, bhh, z4, 0, 0, 0);
#pragma unroll
    for (int r = 0; r < 4; ++r) {
      pw[(q * 4 + r) * 64 + c] = pwc[r];
      ph[(q * 4 + r) * 68 + c] = phc[r] - SHIFT2;
    }
  }

  // pw lookups are ny-invariant per lane in the transposed scheme: hoist.
  float pwv[2][4];
#pragma unroll
  for (int nt2 = 0; nt2 < 2; ++nt2)
#pragma unroll
    for (int r = 0; r < 4; ++r)
      pwv[nt2][r] = pw[il * 64 + (nt2 * 16 + q * 4 + r) - mxb - il + 31];

  v4f oacc = z4;
  float sacc = 0.f;
  const unsigned short* kbase = dq + KS_US + (size_t)bh * 16384;
  const unsigned short* vbase = dq + VTS_US + (size_t)bh * 16384;

  // depth-1 prefetch of ny=0 K/V fragments (branchless; q>=2 re-reads
  // q0/q1's cache lines, dedup'd in L1)
  v8s kb0 = *(const v8s*)(kbase + (il) * 16 + (q & 1) * 8);
  v8s kb1 = *(const v8s*)(kbase + (16 + il) * 16 + (q & 1) * 8);
  v8s vb0 = *(const v8s*)(vbase + (il) * 32 + q * 8);

  for (int ny = 0; ny < 32; ++ny) {
    v8s kc0 = kb0;          // no mask needed: B=qa zero at k>=16
    v8s kc1 = kb1;
    v8s vcur = vb0;
    if (ny < 31) {   // issue next-ny loads; land under softmax + PV below
      kb0 = *(const v8s*)(kbase + ((ny + 1) * 32 + il) * 16 + (q & 1) * 8);
      kb1 = *(const v8s*)(kbase + ((ny + 1) * 32 + 16 + il) * 16 + (q & 1) * 8);
      vb0 = *(const v8s*)(vbase + ((ny + 1) * 16 + il) * 32 + q * 8);
    }
    float phv = ph[il * 68 + (ny - my + 31)];
    v4f s[2];
    s[0] = __builtin_amdgcn_mfma_f32_16x16x32_bf16(kc0, qa, z4, 0, 0, 0);
    s[1] = __builtin_amdgcn_mfma_f32_16x16x32_bf16(kc1, qa, z4, 0, 0, 0);
#pragma unroll
    for (int nt2 = 0; nt2 < 2; ++nt2) {
      float p[4];
#pragma unroll
      for (int r = 0; r < 4; ++r) {
        float t = s[nt2][r] + pwv[nt2][r] + phv;
        p[r] = exp2f(t);
        sacc += p[r];
      }
      uint2 pk;
      pk.x = (unsigned)f2bs(p[0]) | ((unsigned)f2bs(p[1]) << 16);
      pk.y = (unsigned)f2bs(p[2]) | ((unsigned)f2bs(p[3]) << 16);
      *(uint2*)(pl + il * 40 + nt2 * 16 + q * 4) = pk;
    }
    v8s pf = *(const v8s*)(pl + il * 40 + q * 8);
    oacc = __builtin_amdgcn_mfma_f32_16x16x32_bf16(pf, vcur, oacc, 0, 0, 0);
  }

  // row sums: lane holds partial for row il; combine quads, then fetch per-r.
  sacc += __shfl_xor(sacc, 16);
  sacc += __shfl_xor(sacc, 32);

  unsigned short* abase = (b < 6) ? (dq + ART1_US + (size_t)b * 131072)
                                  : (wsart + (size_t)(b - 6) * 131072);
#pragma unroll
  for (int r = 0; r < 4; ++r) {
    float sr = __shfl(sacc, q * 4 + r);       // full sum for row q*4+r
    int m = m0 + q * 4 + r;
    int c = h * 16 + (m >> 6);                // ci of art
    int pp = (m & 63) * 16 + il;              // pos' of art
    abase[((c >> 5) * 1024 + pp) * 32 + (c & 31)] = f2bs(oacc[r] / sr);
  }
}

// ---------------------------------------------------------------------------
// attn_out GEMM: A from artX (contiguous), B from WA2 (frag-major).
// 4 waves/block; wave (mh,nh) owns the 2x2 quadrant.
// 1D grid 256, b = bx&7 pins batch to XCD (art slice L2-resident).
__global__ __launch_bounds__(256) void attn_out_mfma(
    const unsigned short* __restrict__ dq, const unsigned short* __restrict__ wsart,
    const unsigned short* __restrict__ wa2, const float* __restrict__ ba,
    float* __restrict__ out) {
  int tid = threadIdx.x;
  int lane = tid & 63; int il = lane & 15, q = lane >> 4;
  int wv = tid >> 6; int mh = wv >> 1, nh = wv & 1;
  int bx = blockIdx.x;
  int b = bx & 7, pt = (bx >> 3) & 15, coG = bx >> 7;
  int pp0 = pt * 64;
  const unsigned short* ab = (b < 6) ? (dq + ART1_US + (size_t)b * 131072)
                                     : (wsart + (size_t)(b - 6) * 131072);
  const unsigned short* bt = wa2 + (size_t)coG * 8192 + lane * 8;
  v4f acc[2][2];
#pragma unroll
  for (int mi = 0; mi < 2; ++mi)
#pragma unroll
    for (int ni = 0; ni < 2; ++ni) acc[mi][ni] = (v4f){0.f, 0.f, 0.f, 0.f};
#pragma unroll
  for (int kc = 0; kc < 4; ++kc) {
    v8s af[2], bf[2];
#pragma unroll
    for (int ni = 0; ni < 2; ++ni)
      bf[ni] = *(const v8s*)(bt + ((nh * 2 + ni) * 4 + kc) * 512);
#pragma unroll
    for (int mi = 0; mi < 2; ++mi)
      af[mi] = *(const v8s*)(ab + (kc * 1024 + pp0 + (mh * 2 + mi) * 16 + il) * 32 + q * 8);
#pragma unroll
    for (int mi = 0; mi < 2; ++mi)
#pragma unroll
      for (int ni = 0; ni < 2; ++ni)
        acc[mi][ni] = __builtin_amdgcn_mfma_f32_16x16x32_bf16(
            af[mi], bf[ni], acc[mi][ni], 0, 0, 0);
  }
  int co0 = coG * 64;
#pragma unroll
  for (int ni = 0; ni < 2; ++ni) {
    int co = co0 + (nh * 2 + ni) * 16 + il;
    float bias = ba[co];
#pragma unroll
    for (int mi = 0; mi < 2; ++mi) {
      int mt = mh * 2 + mi;
      v4f a = acc[mi][ni];
      float4 v; v.x = a[0] + bias; v.y = a[1] + bias;
      v.z = a[2] + bias; v.w = a[3] + bias;
      *(float4*)(out + ((size_t)(b * 512 + 384 + co)) * 1024 + pp0 + mt * 16 + q * 4) = v;
    }
  }
}

// ---------------------------------------------------------------------------
// conv3x3 via MFMA (v6, kept from R10). Block 512 thr = 8 waves, 128 pos x
// 96 cout (wave = mh(0..3) x nh(0..1), tile 32pos x 48cout, 6 MFMA/tap).
// W tile [6 nfg][9 tap][512us] (54KB) + X tile (13KB) DOUBLE-BUFFERED
// (137KB LDS, 1 block/CU). stage(kc+1) issued async before computing kc;
// ONE barrier per kc drains it (loads had the whole compute window to land).
// Grid (64,4): b = bx&7 pins batch to XCD.
__global__ __launch_bounds__(512) void conv_mfma(
    const unsigned short* __restrict__ xc, const unsigned short* __restrict__ wb3,
    const float* __restrict__ bo, float* __restrict__ out) {
  __shared__ unsigned short xlds[2][6656];    // 13 slots x 512 each buf
  __shared__ unsigned short wlds[2][27648];   // 54 slots x 512 each buf
  int tid = threadIdx.x;
  int lane = tid & 63; int il = lane & 15, q = lane >> 4;
  int wv = tid >> 6; int mh = wv >> 1, nh = wv & 1;
  int bx = blockIdx.x, nset = blockIdx.y;
  int b = bx & 7, pt = bx >> 3;             // pt 0..7; b fastest => XCD-pinned
  int pos0 = pt * 128, y0 = pt * 4;
  const unsigned short* xb = xc + ((size_t)(b * 8) * 1156 + y0 * 34) * 32;

  v4f acc[2][3];
#pragma unroll
  for (int mi = 0; mi < 2; ++mi)
#pragma unroll
    for (int j = 0; j < 3; ++j) acc[mi][j] = (v4f){0.f, 0.f, 0.f, 0.f};

  // X: lds chunk c=(row*4+q)*34+x <- global chunk row*136+x*4+q of slice kc.
  auto stageX = [&](int buf, int kc) {
    const unsigned short* src = xb + (size_t)kc * 36992;   // 1156*32
#pragma unroll
    for (int t = 0; t < 2; ++t) {
      int s = wv + t * 8;                   // wave-uniform slot
      if (s < 13) {
        int c = s * 64 + lane;
        int row = c / 136, rem = c % 136;
        int qv = rem / 34, xx = rem % 34;
        const unsigned short* g = src + ((row * 136 + xx * 4 + qv) << 3);
        __builtin_amdgcn_global_load_lds(
            (const __attribute__((address_space(1))) void*)g,
            (__attribute__((address_space(3))) void*)(&xlds[buf][s * 512]),
            16, 0, 0);
      }
    }
  };

  // W: lds [nfg][tap][512] <- WB3[(nset*6+nfg)][kc][tap]; slot s: nfg=s/9,tap=s%9.
  auto stageW = [&](int buf, int kc) {
#pragma unroll
    for (int t = 0; t < 7; ++t) {
      int s = wv + t * 8;                   // wave-uniform slot
      if (s < 54) {
        int nfg = s / 9, tp = s % 9;
        const unsigned short* g = wb3 +
            ((size_t)(((nset * 6 + nfg) * 8 + kc) * 9 + tp) * 512 + lane * 8);
        __builtin_amdgcn_global_load_lds(
            (const __attribute__((address_space(1))) void*)g,
            (__attribute__((address_space(3))) void*)(&wlds[buf][s * 512]),
            16, 0, 0);
      }
    }
  };

  stageX(0, 0);
  stageW(0, 0);
  __syncthreads();

  for (int kc = 0; kc < 8; ++kc) {
    int cur = kc & 1;
    if (kc < 7) {                           // async prefetch of kc+1
      stageX(cur ^ 1, kc + 1);
      stageW(cur ^ 1, kc + 1);
    }
#pragma unroll
    for (int tap = 0; tap < 9; ++tap) {
      int ky = tap / 3, kx = tap % 3;
      v8s af[2], bf[3];
#pragma unroll
      for (int j = 0; j < 3; ++j)
        bf[j] = *(const v8s*)&wlds[cur][((nh * 3 + j) * 9 + tap) * 512 + lane * 8];
#pragma unroll
      for (int mi = 0; mi < 2; ++mi) {
        int mf = mh * 2 + mi;
        af[mi] = *(const v8s*)&xlds[cur][((((mf >> 1) + ky) * 4 + q) * 34 +
                                          ((mf & 1) * 16 + kx + il)) * 8];
      }
#pragma unroll
      for (int mi = 0; mi < 2; ++mi)
#pragma unroll
        for (int j = 0; j < 3; ++j)
          acc[mi][j] = __builtin_amdgcn_mfma_f32_16x16x32_bf16(
              af[mi], bf[j], acc[mi][j], 0, 0, 0);
    }
    __syncthreads();   // all reads of cur done + prefetch into cur^1 drained
  }

  int co0 = nset * 96;
#pragma unroll
  for (int j = 0; j < 3; ++j) {
    int co = co0 + (nh * 3 + j) * 16 + il;
    float bias = bo[co];
#pragma unroll
    for (int mi = 0; mi < 2; ++mi) {
      int mf = mh * 2 + mi;
      v4f a = acc[mi][j];
      float4 v; v.x = a[0] + bias; v.y = a[1] + bias;
      v.z = a[2] + bias; v.w = a[3] + bias;
      *(float4*)(out + ((size_t)(b * 512 + co)) * 1024 +
                 pos0 + mf * 16 + q * 4) = v;
    }
  }
}

// ---------------------------------------------------------------------------
extern "C" void kernel_launch(void* const* d_in, const int* in_sizes, int n_in,
                              void* d_out, int out_size, void* d_ws, size_t ws_size,
                              hipStream_t stream) {
  const float* x      = (const float*)d_in[0];
  const float* b_out  = (const float*)d_in[2];
  const float* b_kqv  = (const float*)d_in[4];
  const float* b_attn = (const float*)d_in[6];
  const float* krw    = (const float*)d_in[7];
  const float* krh    = (const float*)d_in[8];
  unsigned short* ws = (unsigned short*)d_ws;
  float* out = (float*)d_out;
  unsigned short* dq = (unsigned short*)d_out;

  prep_kernel<<<4556, 256, 0, stream>>>(
      (const float*)d_in[1], (const float*)d_in[3], (const float*)d_in[5],
      krw, krh, x, ws);
  kqv_mfma<<<768, 256, 0, stream>>>(
      ws + XC_US, ws + WK2_US, b_kqv, dq);
  attn_mfma<<<dim3(64, 16), 256, 0, stream>>>(
      dq, ws + KRWB_US, ws + KRHB_US, ws + ART2_US);
  attn_out_mfma<<<256, 256, 0, stream>>>(
      dq, ws + ART2_US, ws + WA2_US, b_attn, out);
  conv_mfma<<<dim3(64, 4), 512, 0, stream>>>(
      ws + XC_US, ws + WB2_US, b_out, out);
}

// Round 12
// 143.676 us; speedup vs baseline: 1.0308x; 1.0035x over previous
//
#include <hip/hip_runtime.h>
#include <hip/hip_bf16.h>

// ---------------------------------------------------------------------------
// SelfAttention2d, fully-MFMA pipeline, fragment-major memory layouts.
// MFMA 16x16x32 bf16: A[m=il][k=q*8+j], B[col=il][k=q*8+j], C[row=q*4+r][col=il]
//
// R12: pipeline-depth round. (a) attn: depth-2 BRANCHLESS K/V prefetch —
// named A/B slot rotation in a ny+=2 loop (static regs); loads for ny+2/3
// issued unconditionally (1-iter overrun lands in adjacent valid scratch,
// values never consumed). Each load gets ~2 bodies (>=400cy) of slack vs ~1.
// (b) kqv: 6-slot depth-5 rolling prefetch (was 4-slot depth-3 ~60cy cover
// vs ~200cy L2 latency); (kc+5)%6 != kc%6 so no consume/overwrite collision;
// ~135 VGPR keeps 3 waves/SIMD -> 768 blocks still single-pass.
//
// Attention computes S TRANSPOSED (A=K, B=Q) so each lane holds
// S[m=m0+il][n=nb+q*4+r]:  pw lookups become ny-invariant registers, ph is one
// read/ny, and P needs only an 8B LDS write + b128 read to become the PV
// A-operand (full K=32).
//
// Layouts:
//   XC   [b][kc 0..7][y 0..33][x 0..33][ci 32]  zero-padded image, bf16
//   WB3  [coG6][nt4][kc8][tap9][lane64][8]      w_out frag-major
//   WK2  [coG6][nt4][kc8][lane64][8]            w_kqv frag-major
//   WA2  [coG2][nt4][kc4][lane64][8]            w_attn frag-major
//   VT   [bh][ny32][d16][ci 32]                 V^T frag-major
//   artX [b][kc4][pp1024][ci32]                 attn out, frag-major
//
// ws (ushort units, 7,262,208 B <= proven-safe 8,192,000):
//   WB3 0 / WK2 884736 / WA2 983040 / KRWB 999424 / KRHB 1000448 /
//   XC 1001472 (2,367,488) / ART2 3368960 (b=6,7 slots)
// d_out scratch (ushort): KS 0 / QS 1048576 / VT 2097152 / ART1 7340032 (b0..5)
// Order: prep(+ring+xt) -> kqv -> attn -> attn_out -> conv
// ---------------------------------------------------------------------------

typedef short v8s __attribute__((ext_vector_type(8)));
typedef float v4f __attribute__((ext_vector_type(4)));

#define WB2_US   0u
#define WK2_US   884736u
#define WA2_US   983040u
#define KRWB_US  999424u
#define KRHB_US  1000448u
#define XC_US    1001472u
#define ART2_US  3368960u

#define KS_US    0u
#define QS_US    1048576u
#define VTS_US   2097152u
#define ART1_US  7340032u

#define QSCALE 0.360673760f   // 0.25 * log2(e)
#define SHIFT2 17.3123405f    // 12 * log2(e)

__device__ __forceinline__ unsigned short f2bs(float f) {
  __hip_bfloat16 h = __float2bfloat16(f);
  return *reinterpret_cast<unsigned short*>(&h);
}

// ---------------------------------------------------------------------------
// Fused: [0,3912) weight/KR transform; [3912,4044) XC pad-ring zero;
// [4044,4556) xt (x fp32 -> XC interior bf16).
__global__ __launch_bounds__(256) void prep_kernel(
    const float* __restrict__ w_out, const float* __restrict__ w_kqv,
    const float* __restrict__ w_attn, const float* __restrict__ krw,
    const float* __restrict__ krh, const float* __restrict__ x,
    unsigned short* __restrict__ ws) {
  __shared__ float t[64][65];
  int bx = blockIdx.x;
  if (bx < 3912) {
    int i = bx * 256 + threadIdx.x;
    if (i < 884736) {              // WB3[coG][nt][kc][tap][lane][8]
      int j = i & 7, l = (i >> 3) & 63;
      int r = i >> 9;              // fragment chunk index [coG][nt][kc][tap]
      int tap = r % 9; int r2 = r / 9;
      int kc = r2 & 7, nt = (r2 >> 3) & 3, coG = r2 >> 5;
      int co = coG * 64 + nt * 16 + (l & 15);
      int ci = kc * 32 + (l >> 4) * 8 + j;
      ws[WB2_US + i] = f2bs(w_out[(size_t)co * 2304 + ci * 9 + tap]);
    } else if (i < 983040) {       // WK2[coG][nt][kc][lane][8]
      int o = i - 884736;
      int j = o & 7, l = (o >> 3) & 63, kc = (o >> 9) & 7, nt = (o >> 12) & 3;
      int coG = o >> 14;
      int co = coG * 64 + nt * 16 + (l & 15);
      int ci = kc * 32 + (l >> 4) * 8 + j;
      ws[WK2_US + o] = f2bs(w_kqv[co * 256 + ci]);
    } else if (i < 999424) {       // WA2[coG][nt][kc][lane][8]
      int o = i - 983040;
      int j = o & 7, l = (o >> 3) & 63, kc = (o >> 9) & 3, nt = (o >> 11) & 3;
      int coG = o >> 13;
      int co = coG * 64 + nt * 16 + (l & 15);
      int ci = kc * 32 + (l >> 4) * 8 + j;
      ws[WA2_US + o] = f2bs(w_attn[co * 128 + ci]);
    } else if (i < 1000448) {      // krw bf16 [64][16], row 63 zero
      int j = i - 999424; int c = j >> 4, d = j & 15;
      ws[KRWB_US + j] = (c < 63) ? f2bs(krw[c * 16 + d]) : (unsigned short)0;
    } else if (i < 1001472) {
      int j = i - 1000448; int c = j >> 4, d = j & 15;
      ws[KRHB_US + j] = (c < 63) ? f2bs(krh[c * 16 + d]) : (unsigned short)0;
    }
  } else if (bx < 4044) {
    // XC pad ring: 64 slices x 132 pixels x 4 uint4. 33792 uint4 total.
    int g = (bx - 3912) * 256 + threadIdx.x;
    int slice = g / 528, rem = g % 528;
    int pix = rem >> 2, d = rem & 3;
    int y, xx;
    if (pix < 34)       { y = 0;        xx = pix; }
    else if (pix < 68)  { y = 33;       xx = pix - 34; }
    else if (pix < 100) { y = pix - 67; xx = 0; }
    else                { y = pix - 99; xx = 33; }
    uint4 z = {0u, 0u, 0u, 0u};
    ((uint4*)(ws + XC_US))[(slice * 1156 + y * 34 + xx) * 4 + d] = z;
  } else {
    // xt: x [b][ci][pos] fp32 -> XC[b][ci>>5][y+1][x+1][ci&31] bf16.
    int blk = bx - 4044;
    int tid = threadIdx.x; int pl = tid & 63, cg = tid >> 6;
    int pos0 = (blk & 15) * 64, ci0 = ((blk >> 4) & 3) * 64, b = blk >> 6;
    unsigned short* xc = ws + XC_US;
    const float* xb = x + ((size_t)(b * 256 + ci0)) * 1024 + pos0;
#pragma unroll
    for (int i = 0; i < 16; ++i) {
      int ci_l = cg * 16 + i;
      t[ci_l][pl] = xb[(size_t)ci_l * 1024 + pl];
    }
    __syncthreads();
#pragma unroll
    for (int i = 0; i < 16; ++i) {
      int pos_l = cg * 16 + i;
      int pos = pos0 + pos_l;
      int y = (pos >> 5) + 1, xx = (pos & 31) + 1;
      int ci = ci0 + pl;
      xc[((size_t)((b * 8 + (ci >> 5)) * 34 + y) * 34 + xx) * 32 + (ci & 31)] =
          f2bs(t[pl][pos_l]);
    }
  }
}

// ---------------------------------------------------------------------------
// kqv GEMM: A-frags from XC (tap 1,1; contiguous 1KB loads), B from WK2.
// 4 waves/block; wave (mh,nh) owns the 2x2 quadrant (mt=mh*2+mi, nt=nh*2+ni).
// R12: full kc unroll + 6-slot depth-5 rolling prefetch of A/B fragments
// (~5 bodies of slack >= L2 latency; (kc+5)%6 != kc%6, no slot collision).
// 1D grid 768, b = bx&7 pins batch to XCD (XC slice + WK2 L2-resident).
__global__ __launch_bounds__(256) void kqv_mfma(
    const unsigned short* __restrict__ xc, const unsigned short* __restrict__ wk2,
    const float* __restrict__ bkqv, unsigned short* __restrict__ dq) {
  int tid = threadIdx.x;
  int lane = tid & 63; int il = lane & 15, q = lane >> 4;
  int wv = tid >> 6; int mh = wv >> 1, nh = wv & 1;
  int bx = blockIdx.x;
  int b = bx & 7, pt = (bx >> 3) & 15, coG = bx >> 7;
  int pos0 = pt * 64;
  int row0 = pos0 >> 5;
  v4f acc[2][2];
#pragma unroll
  for (int mi = 0; mi < 2; ++mi)
#pragma unroll
    for (int ni = 0; ni < 2; ++ni) acc[mi][ni] = (v4f){0.f, 0.f, 0.f, 0.f};

  int pix[2];
#pragma unroll
  for (int mi = 0; mi < 2; ++mi)
    pix[mi] = (row0 + mh + 1) * 34 + (mi * 16 + il + 1);
  const unsigned short* bt = wk2 + (size_t)coG * 16384 + lane * 8;
  const unsigned short* at = xc + (size_t)(b * 8) * 36992 + q * 8;

  v8s afS[6][2], bfS[6][2];
  // prologue: preload kc = 0..4 into slots 0..4
#pragma unroll
  for (int p = 0; p < 5; ++p) {
#pragma unroll
    for (int ni = 0; ni < 2; ++ni)
      bfS[p][ni] = *(const v8s*)(bt + ((nh * 2 + ni) * 8 + p) * 512);
#pragma unroll
    for (int mi = 0; mi < 2; ++mi)
      afS[p][mi] = *(const v8s*)(at + (size_t)p * 36992 + pix[mi] * 32);
  }

#pragma unroll
  for (int kc = 0; kc < 8; ++kc) {
    if (kc + 5 < 8) {                      // depth-5 prefetch into slot (kc+5)%6
      int kn = kc + 5, s = (kc + 5) % 6;
#pragma unroll
      for (int ni = 0; ni < 2; ++ni)
        bfS[s][ni] = *(const v8s*)(bt + ((nh * 2 + ni) * 8 + kn) * 512);
#pragma unroll
      for (int mi = 0; mi < 2; ++mi)
        afS[s][mi] = *(const v8s*)(at + (size_t)kn * 36992 + pix[mi] * 32);
    }
    int cs = kc % 6;
#pragma unroll
    for (int mi = 0; mi < 2; ++mi)
#pragma unroll
      for (int ni = 0; ni < 2; ++ni)
        acc[mi][ni] = __builtin_amdgcn_mfma_f32_16x16x32_bf16(
            afS[cs][mi], bfS[cs][ni], acc[mi][ni], 0, 0, 0);
  }
  int co0 = coG * 64;
#pragma unroll
  for (int ni = 0; ni < 2; ++ni) {
    int nt = nh * 2 + ni;
    int cob = co0 + nt * 16;
    int co = cob + il;
    float bias = bkqv[co];
    int cls = cob >> 7;                  // 0:k 1:q 2:v (uniform per nt)
    int h = (cob >> 4) & 7;
    size_t bh = (size_t)(b * 8 + h);
#pragma unroll
    for (int mi = 0; mi < 2; ++mi) {
      int mt = mh * 2 + mi;
      int pos = pos0 + mt * 16 + q * 4;
      v4f a = acc[mi][ni];
#pragma unroll
      for (int r = 0; r < 4; ++r) {
        float v = a[r] + bias;
        int p = pos + r;
        if (cls == 0)      dq[KS_US + bh * 16384 + p * 16 + il] = f2bs(v);
        else if (cls == 1) dq[QS_US + bh * 16384 + p * 16 + il] = f2bs(v * QSCALE);
        else               dq[VTS_US + bh * 16384 + ((p >> 5) * 16 + il) * 32 + (p & 31)] = f2bs(v);
      }
    }
  }
}

// ---------------------------------------------------------------------------
// MFMA attention, S-transposed formulation. Block 256 = 4 waves; wave owns a
// 16-row m-tile. Lane (q,il) reg r holds S[m0+il][nb+q*4+r].
// bh on blockIdx.x (XCD = h, K/V L2-resident per XCD).
// R12: depth-2 BRANCHLESS K/V prefetch via named A/B slot rotation (ny+=2
// loop, all-static regs). Loads for ny+2/ny+3 are unconditional — the
// 1-iteration overrun reads adjacent valid scratch (QS/VTS regions) and the
// values are never consumed.
__global__ __launch_bounds__(256) void attn_mfma(
    unsigned short* __restrict__ dq, const unsigned short* __restrict__ krwb,
    const unsigned short* __restrict__ krhb, unsigned short* __restrict__ wsart) {
  __shared__ float lds[4][2448];
  int tid = threadIdx.x; int w = tid >> 6, lane = tid & 63;
  int il = lane & 15, q = lane >> 4;
  int bh = blockIdx.x; int b = bh >> 3, h = bh & 7;
  int m0 = blockIdx.y * 64 + w * 16;
  int my = m0 >> 5, mxb = m0 & 31;
  float* pw = lds[w];                       // [16 rows][stride 64]
  float* ph = pw + 1024;                    // [16 rows][stride 68], - SHIFT2
  unsigned short* pl = (unsigned short*)(ph + 1088);  // [16 rows][stride 40] bf16

  const v8s z8 = {0, 0, 0, 0, 0, 0, 0, 0};
  const v4f z4 = {0.f, 0.f, 0.f, 0.f};

  // Q frag: A-layout for table build == B-layout for S^T (same registers).
  // Zeroed for q>=2 (k>=16): this zero makes all A-side masks unnecessary.
  const unsigned short* qrow = dq + QS_US + (size_t)bh * 16384 + (m0 + il) * 16;
  v8s qa = *(const v8s*)(qrow + (q & 1) * 8);
  qa = (q < 2) ? qa : z8;

  // PW / PH tables via MFMA (A=qa zeroed at k>=16; B-side garbage is harmless)
#pragma unroll
  for (int nt = 0; nt < 4; ++nt) {
    int c = nt * 16 + il;
    v8s bw = *(const v8s*)(krwb + c * 16 + (q & 1) * 8);
    v8s bhh = *(const v8s*)(krhb + c * 16 + (q & 1) * 8);
    v4f pwc = __builtin_amdgcn_mfma_f32_16x16x32_bf16(qa, bw, z4, 0, 0, 0);
    v4f phc = __builtin_amdgcn_mfma_f32_16x16x32_bf16(qa, bhh, z4, 0, 0, 0);
#pragma unroll
    for (int r = 0; r < 4; ++r) {
      pw[(q * 4 + r) * 64 + c] = pwc[r];
      ph[(q * 4 + r) * 68 + c] = phc[r] - SHIFT2;
    }
  }

  // pw lookups are ny-invariant per lane in the transposed scheme: hoist.
  float pwv[2][4];
#pragma unroll
  for (int nt2 = 0; nt2 < 2; ++nt2)
#pragma unroll
    for (int r = 0; r < 4; ++r)
      pwv[nt2][r] = pw[il * 64 + (nt2 * 16 + q * 4 + r) - mxb - il + 31];

  v4f oacc = z4;
  float sacc = 0.f;
  const unsigned short* kbase = dq + KS_US + (size_t)bh * 16384;
  const unsigned short* vbase = dq + VTS_US + (size_t)bh * 16384;

  auto ldk = [&](int ny, int half) -> v8s {
    return *(const v8s*)(kbase + (ny * 32 + half * 16 + il) * 16 + (q & 1) * 8);
  };
  auto ldv = [&](int ny) -> v8s {
    return *(const v8s*)(vbase + (ny * 16 + il) * 32 + q * 8);
  };

  // one body: S MFMAs -> softmax numerators -> P pack -> PV MFMA
  auto body = [&](v8s kc0, v8s kc1, v8s vcur, int ny) {
    float phv = ph[il * 68 + (ny - my + 31)];
    v4f s[2];
    s[0] = __builtin_amdgcn_mfma_f32_16x16x32_bf16(kc0, qa, z4, 0, 0, 0);
    s[1] = __builtin_amdgcn_mfma_f32_16x16x32_bf16(kc1, qa, z4, 0, 0, 0);
#pragma unroll
    for (int nt2 = 0; nt2 < 2; ++nt2) {
      float p[4];
#pragma unroll
      for (int r = 0; r < 4; ++r) {
        float t = s[nt2][r] + pwv[nt2][r] + phv;
        p[r] = exp2f(t);
        sacc += p[r];
      }
      uint2 pk;
      pk.x = (unsigned)f2bs(p[0]) | ((unsigned)f2bs(p[1]) << 16);
      pk.y = (unsigned)f2bs(p[2]) | ((unsigned)f2bs(p[3]) << 16);
      *(uint2*)(pl + il * 40 + nt2 * 16 + q * 4) = pk;
    }
    v8s pf = *(const v8s*)(pl + il * 40 + q * 8);
    oacc = __builtin_amdgcn_mfma_f32_16x16x32_bf16(pf, vcur, oacc, 0, 0, 0);
  };

  // depth-2 prologue: ny=0 (A), ny=1 (B)
  v8s kA0 = ldk(0, 0), kA1 = ldk(0, 1), vA = ldv(0);
  v8s kB0 = ldk(1, 0), kB1 = ldk(1, 1), vB = ldv(1);

  for (int ny = 0; ny < 32; ny += 2) {
    v8s nA0 = ldk(ny + 2, 0), nA1 = ldk(ny + 2, 1), nvA = ldv(ny + 2);
    body(kA0, kA1, vA, ny);
    kA0 = nA0; kA1 = nA1; vA = nvA;
    v8s nB0 = ldk(ny + 3, 0), nB1 = ldk(ny + 3, 1), nvB = ldv(ny + 3);
    body(kB0, kB1, vB, ny + 1);
    kB0 = nB0; kB1 = nB1; vB = nvB;
  }

  // row sums: lane holds partial for row il; combine quads, then fetch per-r.
  sacc += __shfl_xor(sacc, 16);
  sacc += __shfl_xor(sacc, 32);

  unsigned short* abase = (b < 6) ? (dq + ART1_US + (size_t)b * 131072)
                                  : (wsart + (size_t)(b - 6) * 131072);
#pragma unroll
  for (int r = 0; r < 4; ++r) {
    float sr = __shfl(sacc, q * 4 + r);       // full sum for row q*4+r
    int m = m0 + q * 4 + r;
    int c = h * 16 + (m >> 6);                // ci of art
    int pp = (m & 63) * 16 + il;              // pos' of art
    abase[((c >> 5) * 1024 + pp) * 32 + (c & 31)] = f2bs(oacc[r] / sr);
  }
}

// ---------------------------------------------------------------------------
// attn_out GEMM: A from artX (contiguous), B from WA2 (frag-major).
// 4 waves/block; wave (mh,nh) owns the 2x2 quadrant.
// 1D grid 256, b = bx&7 pins batch to XCD (art slice L2-resident).
__global__ __launch_bounds__(256) void attn_out_mfma(
    const unsigned short* __restrict__ dq, const unsigned short* __restrict__ wsart,
    const unsigned short* __restrict__ wa2, const float* __restrict__ ba,
    float* __restrict__ out) {
  int tid = threadIdx.x;
  int lane = tid & 63; int il = lane & 15, q = lane >> 4;
  int wv = tid >> 6; int mh = wv >> 1, nh = wv & 1;
  int bx = blockIdx.x;
  int b = bx & 7, pt = (bx >> 3) & 15, coG = bx >> 7;
  int pp0 = pt * 64;
  const unsigned short* ab = (b < 6) ? (dq + ART1_US + (size_t)b * 131072)
                                     : (wsart + (size_t)(b - 6) * 131072);
  const unsigned short* bt = wa2 + (size_t)coG * 8192 + lane * 8;
  v4f acc[2][2];
#pragma unroll
  for (int mi = 0; mi < 2; ++mi)
#pragma unroll
    for (int ni = 0; ni < 2; ++ni) acc[mi][ni] = (v4f){0.f, 0.f, 0.f, 0.f};
#pragma unroll
  for (int kc = 0; kc < 4; ++kc) {
    v8s af[2], bf[2];
#pragma unroll
    for (int ni = 0; ni < 2; ++ni)
      bf[ni] = *(const v8s*)(bt + ((nh * 2 + ni) * 4 + kc) * 512);
#pragma unroll
    for (int mi = 0; mi < 2; ++mi)
      af[mi] = *(const v8s*)(ab + (kc * 1024 + pp0 + (mh * 2 + mi) * 16 + il) * 32 + q * 8);
#pragma unroll
    for (int mi = 0; mi < 2; ++mi)
#pragma unroll
      for (int ni = 0; ni < 2; ++ni)
        acc[mi][ni] = __builtin_amdgcn_mfma_f32_16x16x32_bf16(
            af[mi], bf[ni], acc[mi][ni], 0, 0, 0);
  }
  int co0 = coG * 64;
#pragma unroll
  for (int ni = 0; ni < 2; ++ni) {
    int co = co0 + (nh * 2 + ni) * 16 + il;
    float bias = ba[co];
#pragma unroll
    for (int mi = 0; mi < 2; ++mi) {
      int mt = mh * 2 + mi;
      v4f a = acc[mi][ni];
      float4 v; v.x = a[0] + bias; v.y = a[1] + bias;
      v.z = a[2] + bias; v.w = a[3] + bias;
      *(float4*)(out + ((size_t)(b * 512 + 384 + co)) * 1024 + pp0 + mt * 16 + q * 4) = v;
    }
  }
}

// ---------------------------------------------------------------------------
// conv3x3 via MFMA (v6). Block 512 thr = 8 waves, 128 pos x 96 cout
// (wave = mh(0..3) x nh(0..1), tile 32pos x 48cout, 6 MFMA/tap).
// W tile [6 nfg][9 tap][512us] (54KB) + X tile (13KB) DOUBLE-BUFFERED
// (137KB LDS, 1 block/CU). stage(kc+1) issued async before computing kc;
// ONE barrier per kc drains it (loads had the whole compute window to land).
// Grid (64,4): b = bx&7 pins batch to XCD.
__global__ __launch_bounds__(512) void conv_mfma(
    const unsigned short* __restrict__ xc, const unsigned short* __restrict__ wb3,
    const float* __restrict__ bo, float* __restrict__ out) {
  __shared__ unsigned short xlds[2][6656];    // 13 slots x 512 each buf
  __shared__ unsigned short wlds[2][27648];   // 54 slots x 512 each buf
  int tid = threadIdx.x;
  int lane = tid & 63; int il = lane & 15, q = lane >> 4;
  int wv = tid >> 6; int mh = wv >> 1, nh = wv & 1;
  int bx = blockIdx.x, nset = blockIdx.y;
  int b = bx & 7, pt = bx >> 3;             // pt 0..7; b fastest => XCD-pinned
  int pos0 = pt * 128, y0 = pt * 4;
  const unsigned short* xb = xc + ((size_t)(b * 8) * 1156 + y0 * 34) * 32;

  v4f acc[2][3];
#pragma unroll
  for (int mi = 0; mi < 2; ++mi)
#pragma unroll
    for (int j = 0; j < 3; ++j) acc[mi][j] = (v4f){0.f, 0.f, 0.f, 0.f};

  // X: lds chunk c=(row*4+q)*34+x <- global chunk row*136+x*4+q of slice kc.
  auto stageX = [&](int buf, int kc) {
    const unsigned short* src = xb + (size_t)kc * 36992;   // 1156*32
#pragma unroll
    for (int t = 0; t < 2; ++t) {
      int s = wv + t * 8;                   // wave-uniform slot
      if (s < 13) {
        int c = s * 64 + lane;
        int row = c / 136, rem = c % 136;
        int qv = rem / 34, xx = rem % 34;
        const unsigned short* g = src + ((row * 136 + xx * 4 + qv) << 3);
        __builtin_amdgcn_global_load_lds(
            (const __attribute__((address_space(1))) void*)g,
            (__attribute__((address_space(3))) void*)(&xlds[buf][s * 512]),
            16, 0, 0);
      }
    }
  };

  // W: lds [nfg][tap][512] <- WB3[(nset*6+nfg)][kc][tap]; slot s: nfg=s/9,tap=s%9.
  auto stageW = [&](int buf, int kc) {
#pragma unroll
    for (int t = 0; t < 7; ++t) {
      int s = wv + t * 8;                   // wave-uniform slot
      if (s < 54) {
        int nfg = s / 9, tp = s % 9;
        const unsigned short* g = wb3 +
            ((size_t)(((nset * 6 + nfg) * 8 + kc) * 9 + tp) * 512 + lane * 8);
        __builtin_amdgcn_global_load_lds(
            (const __attribute__((address_space(1))) void*)g,
            (__attribute__((address_space(3))) void*)(&wlds[buf][s * 512]),
            16, 0, 0);
      }
    }
  };

  stageX(0, 0);
  stageW(0, 0);
  __syncthreads();

  for (int kc = 0; kc < 8; ++kc) {
    int cur = kc & 1;
    if (kc < 7) {                           // async prefetch of kc+1
      stageX(cur ^ 1, kc + 1);
      stageW(cur ^ 1, kc + 1);
    }
#pragma unroll
    for (int tap = 0; tap < 9; ++tap) {
      int ky = tap / 3, kx = tap % 3;
      v8s af[2], bf[3];
#pragma unroll
      for (int j = 0; j < 3; ++j)
        bf[j] = *(const v8s*)&wlds[cur][((nh * 3 + j) * 9 + tap) * 512 + lane * 8];
#pragma unroll
      for (int mi = 0; mi < 2; ++mi) {
        int mf = mh * 2 + mi;
        af[mi] = *(const v8s*)&xlds[cur][((((mf >> 1) + ky) * 4 + q) * 34 +
                                          ((mf & 1) * 16 + kx + il)) * 8];
      }
#pragma unroll
      for (int mi = 0; mi < 2; ++mi)
#pragma unroll
        for (int j = 0; j < 3; ++j)
          acc[mi][j] = __builtin_amdgcn_mfma_f32_16x16x32_bf16(
              af[mi], bf[j], acc[mi][j], 0, 0, 0);
    }
    __syncthreads();   // all reads of cur done + prefetch into cur^1 drained
  }

  int co0 = nset * 96;
#pragma unroll
  for (int j = 0; j < 3; ++j) {
    int co = co0 + (nh * 3 + j) * 16 + il;
    float bias = bo[co];
#pragma unroll
    for (int mi = 0; mi < 2; ++mi) {
      int mf = mh * 2 + mi;
      v4f a = acc[mi][j];
      float4 v; v.x = a[0] + bias; v.y = a[1] + bias;
      v.z = a[2] + bias; v.w = a[3] + bias;
      *(float4*)(out + ((size_t)(b * 512 + co)) * 1024 +
                 pos0 + mf * 16 + q * 4) = v;
    }
  }
}

// ---------------------------------------------------------------------------
extern "C" void kernel_launch(void* const* d_in, const int* in_sizes, int n_in,
                              void* d_out, int out_size, void* d_ws, size_t ws_size,
                              hipStream_t stream) {
  const float* x      = (const float*)d_in[0];
  const float* b_out  = (const float*)d_in[2];
  const float* b_kqv  = (const float*)d_in[4];
  const float* b_attn = (const float*)d_in[6];
  const float* krw    = (const float*)d_in[7];
  const float* krh    = (const float*)d_in[8];
  unsigned short* ws = (unsigned short*)d_ws;
  float* out = (float*)d_out;
  unsigned short* dq = (unsigned short*)d_out;

  prep_kernel<<<4556, 256, 0, stream>>>(
      (const float*)d_in[1], (const float*)d_in[3], (const float*)d_in[5],
      krw, krh, x, ws);
  kqv_mfma<<<768, 256, 0, stream>>>(
      ws + XC_US, ws + WK2_US, b_kqv, dq);
  attn_mfma<<<dim3(64, 16), 256, 0, stream>>>(
      dq, ws + KRWB_US, ws + KRHB_US, ws + ART2_US);
  attn_out_mfma<<<256, 256, 0, stream>>>(
      dq, ws + ART2_US, ws + WA2_US, b_attn, out);
  conv_mfma<<<dim3(64, 4), 512, 0, stream>>>(
      ws + XC_US, ws + WB2_US, b_out, out);
}

// Round 13
// 142.427 us; speedup vs baseline: 1.0398x; 1.0088x over previous
//
#include <hip/hip_runtime.h>
#include <hip/hip_bf16.h>

// ---------------------------------------------------------------------------
// SelfAttention2d, fully-MFMA pipeline, fragment-major memory layouts.
// MFMA 16x16x32 bf16: A[m=il][k=q*8+j], B[col=il][k=q*8+j], C[row=q*4+r][col=il]
//
// R13: prep coalescing. Old WB3 transform read w_out at stride 36B (14%
// line utilization -> ~25MB effective traffic for a 3.5MB cold read, at the
// FRONT of the dependency chain). New: block per (coG,nt,kc) stages 16 co x
// 288 contiguous floats to LDS (coalesced), then writes the frag-major chunk
// as contiguous v8s stores gathered from LDS (stride-9 = odd = conflict-free).
// Also: xt block mapping b = blk&7 so XC producer XCD == pinned consumer XCD.
//
// Attention computes S TRANSPOSED (A=K, B=Q) so each lane holds
// S[m=m0+il][n=nb+q*4+r]:  pw lookups become ny-invariant registers, ph is one
// read/ny, and P needs only an 8B LDS write + b128 read to become the PV
// A-operand (full K=32).
//
// Layouts:
//   XC   [b][kc 0..7][y 0..33][x 0..33][ci 32]  zero-padded image, bf16
//   WB3  [coG6][nt4][kc8][tap9][lane64][8]      w_out frag-major
//   WK2  [coG6][nt4][kc8][lane64][8]            w_kqv frag-major
//   WA2  [coG2][nt4][kc4][lane64][8]            w_attn frag-major
//   VT   [bh][ny32][d16][ci 32]                 V^T frag-major
//   artX [b][kc4][pp1024][ci32]                 attn out, frag-major
//
// ws (ushort units, 7,262,208 B <= proven-safe 8,192,000):
//   WB3 0 / WK2 884736 / WA2 983040 / KRWB 999424 / KRHB 1000448 /
//   XC 1001472 (2,367,488) / ART2 3368960 (b=6,7 slots)
// d_out scratch (ushort): KS 0 / QS 1048576 / VT 2097152 / ART1 7340032 (b0..5)
// Order: prep(+ring+xt) -> kqv -> attn -> attn_out -> conv
// ---------------------------------------------------------------------------

typedef short v8s __attribute__((ext_vector_type(8)));
typedef float v4f __attribute__((ext_vector_type(4)));

#define WB2_US   0u
#define WK2_US   884736u
#define WA2_US   983040u
#define KRWB_US  999424u
#define KRHB_US  1000448u
#define XC_US    1001472u
#define ART2_US  3368960u

#define KS_US    0u
#define QS_US    1048576u
#define VTS_US   2097152u
#define ART1_US  7340032u

#define QSCALE 0.360673760f   // 0.25 * log2(e)
#define SHIFT2 17.3123405f    // 12 * log2(e)

__device__ __forceinline__ unsigned short f2bs(float f) {
  __hip_bfloat16 h = __float2bfloat16(f);
  return *reinterpret_cast<unsigned short*>(&h);
}

// ---------------------------------------------------------------------------
// Fused prep. Block ranges:
//   [0,192)    WB3 transform, LDS-staged double-transpose (coalesced both sides)
//   [192,648)  WK2 / WA2 / KR (element-wise, i = (bx-192)*256 + 884736 + tid)
//   [648,780)  XC pad-ring zero
//   [780,1292) xt (x fp32 -> XC interior bf16), b = blk&7 (XCD-aligned)
__global__ __launch_bounds__(256) void prep_kernel(
    const float* __restrict__ w_out, const float* __restrict__ w_kqv,
    const float* __restrict__ w_attn, const float* __restrict__ krw,
    const float* __restrict__ krh, const float* __restrict__ x,
    unsigned short* __restrict__ ws) {
  __shared__ float sh[4640];     // WB3: [16][288]; xt: [64][65]
  int bx = blockIdx.x;
  int tid = threadIdx.x;
  if (bx < 192) {
    // WB3[coG][nt][kc][tap][lane][8] <- w_out, via LDS
    int coG = bx >> 5, rem = bx & 31, nt = rem >> 3, kc = rem & 7;
    int co0 = coG * 64 + nt * 16;
    const float* src = w_out + (size_t)co0 * 2304 + kc * 288;
#pragma unroll
    for (int t = 0; t < 18; ++t) {
      int e = tid + t * 256;               // < 4608
      int row = e / 288, off = e % 288;
      sh[row * 288 + off] = src[(size_t)row * 2304 + off];
    }
    __syncthreads();
    unsigned short* dst = ws + WB2_US +
        (size_t)(((coG * 4 + nt) * 8 + kc) * 9) * 512;
#pragma unroll
    for (int t = 0; t < 3; ++t) {
      int ce = tid + t * 256;              // chunk-of-8 index, < 576
      if (ce < 576) {
        int tap = ce >> 6, l = ce & 63, il = l & 15, lq = l >> 4;
        v8s v;
#pragma unroll
        for (int j = 0; j < 8; ++j)
          v[j] = (short)f2bs(sh[il * 288 + (lq * 8 + j) * 9 + tap]);
        *(v8s*)(dst + tap * 512 + l * 8) = v;
      }
    }
  } else if (bx < 648) {
    int i = (bx - 192) * 256 + tid + 884736;
    if (i < 983040) {              // WK2[coG][nt][kc][lane][8]
      int o = i - 884736;
      int j = o & 7, l = (o >> 3) & 63, kc = (o >> 9) & 7, nt = (o >> 12) & 3;
      int coG = o >> 14;
      int co = coG * 64 + nt * 16 + (l & 15);
      int ci = kc * 32 + (l >> 4) * 8 + j;
      ws[WK2_US + o] = f2bs(w_kqv[co * 256 + ci]);
    } else if (i < 999424) {       // WA2[coG][nt][kc][lane][8]
      int o = i - 983040;
      int j = o & 7, l = (o >> 3) & 63, kc = (o >> 9) & 3, nt = (o >> 11) & 3;
      int coG = o >> 13;
      int co = coG * 64 + nt * 16 + (l & 15);
      int ci = kc * 32 + (l >> 4) * 8 + j;
      ws[WA2_US + o] = f2bs(w_attn[co * 128 + ci]);
    } else if (i < 1000448) {      // krw bf16 [64][16], row 63 zero
      int j = i - 999424; int c = j >> 4, d = j & 15;
      ws[KRWB_US + j] = (c < 63) ? f2bs(krw[c * 16 + d]) : (unsigned short)0;
    } else if (i < 1001472) {
      int j = i - 1000448; int c = j >> 4, d = j & 15;
      ws[KRHB_US + j] = (c < 63) ? f2bs(krh[c * 16 + d]) : (unsigned short)0;
    }
  } else if (bx < 780) {
    // XC pad ring: 64 slices x 132 pixels x 4 uint4. 33792 uint4 total.
    int g = (bx - 648) * 256 + tid;
    int slice = g / 528, rem = g % 528;
    int pix = rem >> 2, d = rem & 3;
    int y, xx;
    if (pix < 34)       { y = 0;        xx = pix; }
    else if (pix < 68)  { y = 33;       xx = pix - 34; }
    else if (pix < 100) { y = pix - 67; xx = 0; }
    else                { y = pix - 99; xx = 33; }
    uint4 z = {0u, 0u, 0u, 0u};
    ((uint4*)(ws + XC_US))[(slice * 1156 + y * 34 + xx) * 4 + d] = z;
  } else {
    // xt: x [b][ci][pos] fp32 -> XC[b][ci>>5][y+1][x+1][ci&31] bf16.
    // b fastest (blk&7) so producer XCD == consumer XCD (kqv/conv pinning).
    int blk = bx - 780;
    int pl = tid & 63, cg = tid >> 6;
    int b = blk & 7, pos0 = ((blk >> 3) & 15) * 64, ci0 = (blk >> 7) * 64;
    unsigned short* xc = ws + XC_US;
    const float* xb = x + ((size_t)(b * 256 + ci0)) * 1024 + pos0;
#pragma unroll
    for (int i = 0; i < 16; ++i) {
      int ci_l = cg * 16 + i;
      sh[ci_l * 65 + pl] = xb[(size_t)ci_l * 1024 + pl];
    }
    __syncthreads();
#pragma unroll
    for (int i = 0; i < 16; ++i) {
      int pos_l = cg * 16 + i;
      int pos = pos0 + pos_l;
      int y = (pos >> 5) + 1, xx = (pos & 31) + 1;
      int ci = ci0 + pl;
      xc[((size_t)((b * 8 + (ci >> 5)) * 34 + y) * 34 + xx) * 32 + (ci & 31)] =
          f2bs(sh[pl * 65 + pos_l]);
    }
  }
}

// ---------------------------------------------------------------------------
// kqv GEMM: A-frags from XC (tap 1,1; contiguous 1KB loads), B from WK2.
// 4 waves/block; wave (mh,nh) owns the 2x2 quadrant (mt=mh*2+mi, nt=nh*2+ni).
// Full kc unroll + 6-slot depth-5 rolling prefetch of A/B fragments.
// 1D grid 768, b = bx&7 pins batch to XCD (XC slice + WK2 L2-resident).
__global__ __launch_bounds__(256) void kqv_mfma(
    const unsigned short* __restrict__ xc, const unsigned short* __restrict__ wk2,
    const float* __restrict__ bkqv, unsigned short* __restrict__ dq) {
  int tid = threadIdx.x;
  int lane = tid & 63; int il = lane & 15, q = lane >> 4;
  int wv = tid >> 6; int mh = wv >> 1, nh = wv & 1;
  int bx = blockIdx.x;
  int b = bx & 7, pt = (bx >> 3) & 15, coG = bx >> 7;
  int pos0 = pt * 64;
  int row0 = pos0 >> 5;
  v4f acc[2][2];
#pragma unroll
  for (int mi = 0; mi < 2; ++mi)
#pragma unroll
    for (int ni = 0; ni < 2; ++ni) acc[mi][ni] = (v4f){0.f, 0.f, 0.f, 0.f};

  int pix[2];
#pragma unroll
  for (int mi = 0; mi < 2; ++mi)
    pix[mi] = (row0 + mh + 1) * 34 + (mi * 16 + il + 1);
  const unsigned short* bt = wk2 + (size_t)coG * 16384 + lane * 8;
  const unsigned short* at = xc + (size_t)(b * 8) * 36992 + q * 8;

  v8s afS[6][2], bfS[6][2];
  // prologue: preload kc = 0..4 into slots 0..4
#pragma unroll
  for (int p = 0; p < 5; ++p) {
#pragma unroll
    for (int ni = 0; ni < 2; ++ni)
      bfS[p][ni] = *(const v8s*)(bt + ((nh * 2 + ni) * 8 + p) * 512);
#pragma unroll
    for (int mi = 0; mi < 2; ++mi)
      afS[p][mi] = *(const v8s*)(at + (size_t)p * 36992 + pix[mi] * 32);
  }

#pragma unroll
  for (int kc = 0; kc < 8; ++kc) {
    if (kc + 5 < 8) {                      // depth-5 prefetch into slot (kc+5)%6
      int kn = kc + 5, s = (kc + 5) % 6;
#pragma unroll
      for (int ni = 0; ni < 2; ++ni)
        bfS[s][ni] = *(const v8s*)(bt + ((nh * 2 + ni) * 8 + kn) * 512);
#pragma unroll
      for (int mi = 0; mi < 2; ++mi)
        afS[s][mi] = *(const v8s*)(at + (size_t)kn * 36992 + pix[mi] * 32);
    }
    int cs = kc % 6;
#pragma unroll
    for (int mi = 0; mi < 2; ++mi)
#pragma unroll
      for (int ni = 0; ni < 2; ++ni)
        acc[mi][ni] = __builtin_amdgcn_mfma_f32_16x16x32_bf16(
            afS[cs][mi], bfS[cs][ni], acc[mi][ni], 0, 0, 0);
  }
  int co0 = coG * 64;
#pragma unroll
  for (int ni = 0; ni < 2; ++ni) {
    int nt = nh * 2 + ni;
    int cob = co0 + nt * 16;
    int co = cob + il;
    float bias = bkqv[co];
    int cls = cob >> 7;                  // 0:k 1:q 2:v (uniform per nt)
    int h = (cob >> 4) & 7;
    size_t bh = (size_t)(b * 8 + h);
#pragma unroll
    for (int mi = 0; mi < 2; ++mi) {
      int mt = mh * 2 + mi;
      int pos = pos0 + mt * 16 + q * 4;
      v4f a = acc[mi][ni];
#pragma unroll
      for (int r = 0; r < 4; ++r) {
        float v = a[r] + bias;
        int p = pos + r;
        if (cls == 0)      dq[KS_US + bh * 16384 + p * 16 + il] = f2bs(v);
        else if (cls == 1) dq[QS_US + bh * 16384 + p * 16 + il] = f2bs(v * QSCALE);
        else               dq[VTS_US + bh * 16384 + ((p >> 5) * 16 + il) * 32 + (p & 31)] = f2bs(v);
      }
    }
  }
}

// ---------------------------------------------------------------------------
// MFMA attention, S-transposed formulation. Block 256 = 4 waves; wave owns a
// 16-row m-tile. Lane (q,il) reg r holds S[m0+il][nb+q*4+r].
// bh on blockIdx.x (XCD = h, K/V L2-resident per XCD).
// Depth-2 BRANCHLESS K/V prefetch via named A/B slot rotation (ny+=2 loop,
// all-static regs). Loads for ny+2/ny+3 are unconditional — the 1-iteration
// overrun reads adjacent valid scratch, values never consumed.
__global__ __launch_bounds__(256) void attn_mfma(
    unsigned short* __restrict__ dq, const unsigned short* __restrict__ krwb,
    const unsigned short* __restrict__ krhb, unsigned short* __restrict__ wsart) {
  __shared__ float lds[4][2448];
  int tid = threadIdx.x; int w = tid >> 6, lane = tid & 63;
  int il = lane & 15, q = lane >> 4;
  int bh = blockIdx.x; int b = bh >> 3, h = bh & 7;
  int m0 = blockIdx.y * 64 + w * 16;
  int my = m0 >> 5, mxb = m0 & 31;
  float* pw = lds[w];                       // [16 rows][stride 64]
  float* ph = pw + 1024;                    // [16 rows][stride 68], - SHIFT2
  unsigned short* pl = (unsigned short*)(ph + 1088);  // [16 rows][stride 40] bf16

  const v8s z8 = {0, 0, 0, 0, 0, 0, 0, 0};
  const v4f z4 = {0.f, 0.f, 0.f, 0.f};

  // Q frag: A-layout for table build == B-layout for S^T (same registers).
  // Zeroed for q>=2 (k>=16): this zero makes all A-side masks unnecessary.
  const unsigned short* qrow = dq + QS_US + (size_t)bh * 16384 + (m0 + il) * 16;
  v8s qa = *(const v8s*)(qrow + (q & 1) * 8);
  qa = (q < 2) ? qa : z8;

  // PW / PH tables via MFMA (A=qa zeroed at k>=16; B-side garbage is harmless)
#pragma unroll
  for (int nt = 0; nt < 4; ++nt) {
    int c = nt * 16 + il;
    v8s bw = *(const v8s*)(krwb + c * 16 + (q & 1) * 8);
    v8s bhh = *(const v8s*)(krhb + c * 16 + (q & 1) * 8);
    v4f pwc = __builtin_amdgcn_mfma_f32_16x16x32_bf16(qa, bw, z4, 0, 0, 0);
    v4f phc = __builtin_amdgcn_mfma_f32_16x16x32_bf16(qa, bhh, z4, 0, 0, 0);
#pragma unroll
    for (int r = 0; r < 4; ++r) {
      pw[(q * 4 + r) * 64 + c] = pwc[r];
      ph[(q * 4 + r) * 68 + c] = phc[r] - SHIFT2;
    }
  }

  // pw lookups are ny-invariant per lane in the transposed scheme: hoist.
  float pwv[2][4];
#pragma unroll
  for (int nt2 = 0; nt2 < 2; ++nt2)
#pragma unroll
    for (int r = 0; r < 4; ++r)
      pwv[nt2][r] = pw[il * 64 + (nt2 * 16 + q * 4 + r) - mxb - il + 31];

  v4f oacc = z4;
  float sacc = 0.f;
  const unsigned short* kbase = dq + KS_US + (size_t)bh * 16384;
  const unsigned short* vbase = dq + VTS_US + (size_t)bh * 16384;

  auto ldk = [&](int ny, int half) -> v8s {
    return *(const v8s*)(kbase + (ny * 32 + half * 16 + il) * 16 + (q & 1) * 8);
  };
  auto ldv = [&](int ny) -> v8s {
    return *(const v8s*)(vbase + (ny * 16 + il) * 32 + q * 8);
  };

  // one body: S MFMAs -> softmax numerators -> P pack -> PV MFMA
  auto body = [&](v8s kc0, v8s kc1, v8s vcur, int ny) {
    float phv = ph[il * 68 + (ny - my + 31)];
    v4f s[2];
    s[0] = __builtin_amdgcn_mfma_f32_16x16x32_bf16(kc0, qa, z4, 0, 0, 0);
    s[1] = __builtin_amdgcn_mfma_f32_16x16x32_bf16(kc1, qa, z4, 0, 0, 0);
#pragma unroll
    for (int nt2 = 0; nt2 < 2; ++nt2) {
      float p[4];
#pragma unroll
      for (int r = 0; r < 4; ++r) {
        float t = s[nt2][r] + pwv[nt2][r] + phv;
        p[r] = exp2f(t);
        sacc += p[r];
      }
      uint2 pk;
      pk.x = (unsigned)f2bs(p[0]) | ((unsigned)f2bs(p[1]) << 16);
      pk.y = (unsigned)f2bs(p[2]) | ((unsigned)f2bs(p[3]) << 16);
      *(uint2*)(pl + il * 40 + nt2 * 16 + q * 4) = pk;
    }
    v8s pf = *(const v8s*)(pl + il * 40 + q * 8);
    oacc = __builtin_amdgcn_mfma_f32_16x16x32_bf16(pf, vcur, oacc, 0, 0, 0);
  };

  // depth-2 prologue: ny=0 (A), ny=1 (B)
  v8s kA0 = ldk(0, 0), kA1 = ldk(0, 1), vA = ldv(0);
  v8s kB0 = ldk(1, 0), kB1 = ldk(1, 1), vB = ldv(1);

  for (int ny = 0; ny < 32; ny += 2) {
    v8s nA0 = ldk(ny + 2, 0), nA1 = ldk(ny + 2, 1), nvA = ldv(ny + 2);
    body(kA0, kA1, vA, ny);
    kA0 = nA0; kA1 = nA1; vA = nvA;
    v8s nB0 = ldk(ny + 3, 0), nB1 = ldk(ny + 3, 1), nvB = ldv(ny + 3);
    body(kB0, kB1, vB, ny + 1);
    kB0 = nB0; kB1 = nB1; vB = nvB;
  }

  // row sums: lane holds partial for row il; combine quads, then fetch per-r.
  sacc += __shfl_xor(sacc, 16);
  sacc += __shfl_xor(sacc, 32);

  unsigned short* abase = (b < 6) ? (dq + ART1_US + (size_t)b * 131072)
                                  : (wsart + (size_t)(b - 6) * 131072);
#pragma unroll
  for (int r = 0; r < 4; ++r) {
    float sr = __shfl(sacc, q * 4 + r);       // full sum for row q*4+r
    int m = m0 + q * 4 + r;
    int c = h * 16 + (m >> 6);                // ci of art
    int pp = (m & 63) * 16 + il;              // pos' of art
    abase[((c >> 5) * 1024 + pp) * 32 + (c & 31)] = f2bs(oacc[r] / sr);
  }
}

// ---------------------------------------------------------------------------
// attn_out GEMM: A from artX (contiguous), B from WA2 (frag-major).
// 4 waves/block; wave (mh,nh) owns the 2x2 quadrant.
// 1D grid 256, b = bx&7 pins batch to XCD (art slice L2-resident).
__global__ __launch_bounds__(256) void attn_out_mfma(
    const unsigned short* __restrict__ dq, const unsigned short* __restrict__ wsart,
    const unsigned short* __restrict__ wa2, const float* __restrict__ ba,
    float* __restrict__ out) {
  int tid = threadIdx.x;
  int lane = tid & 63; int il = lane & 15, q = lane >> 4;
  int wv = tid >> 6; int mh = wv >> 1, nh = wv & 1;
  int bx = blockIdx.x;
  int b = bx & 7, pt = (bx >> 3) & 15, coG = bx >> 7;
  int pp0 = pt * 64;
  const unsigned short* ab = (b < 6) ? (dq + ART1_US + (size_t)b * 131072)
                                     : (wsart + (size_t)(b - 6) * 131072);
  const unsigned short* bt = wa2 + (size_t)coG * 8192 + lane * 8;
  v4f acc[2][2];
#pragma unroll
  for (int mi = 0; mi < 2; ++mi)
#pragma unroll
    for (int ni = 0; ni < 2; ++ni) acc[mi][ni] = (v4f){0.f, 0.f, 0.f, 0.f};
#pragma unroll
  for (int kc = 0; kc < 4; ++kc) {
    v8s af[2], bf[2];
#pragma unroll
    for (int ni = 0; ni < 2; ++ni)
      bf[ni] = *(const v8s*)(bt + ((nh * 2 + ni) * 4 + kc) * 512);
#pragma unroll
    for (int mi = 0; mi < 2; ++mi)
      af[mi] = *(const v8s*)(ab + (kc * 1024 + pp0 + (mh * 2 + mi) * 16 + il) * 32 + q * 8);
#pragma unroll
    for (int mi = 0; mi < 2; ++mi)
#pragma unroll
      for (int ni = 0; ni < 2; ++ni)
        acc[mi][ni] = __builtin_amdgcn_mfma_f32_16x16x32_bf16(
            af[mi], bf[ni], acc[mi][ni], 0, 0, 0);
  }
  int co0 = coG * 64;
#pragma unroll
  for (int ni = 0; ni < 2; ++ni) {
    int co = co0 + (nh * 2 + ni) * 16 + il;
    float bias = ba[co];
#pragma unroll
    for (int mi = 0; mi < 2; ++mi) {
      int mt = mh * 2 + mi;
      v4f a = acc[mi][ni];
      float4 v; v.x = a[0] + bias; v.y = a[1] + bias;
      v.z = a[2] + bias; v.w = a[3] + bias;
      *(float4*)(out + ((size_t)(b * 512 + 384 + co)) * 1024 + pp0 + mt * 16 + q * 4) = v;
    }
  }
}

// ---------------------------------------------------------------------------
// conv3x3 via MFMA (v6). Block 512 thr = 8 waves, 128 pos x 96 cout
// (wave = mh(0..3) x nh(0..1), tile 32pos x 48cout, 6 MFMA/tap).
// W tile [6 nfg][9 tap][512us] (54KB) + X tile (13KB) DOUBLE-BUFFERED
// (137KB LDS, 1 block/CU). stage(kc+1) issued async before computing kc;
// ONE barrier per kc drains it (loads had the whole compute window to land).
// Grid (64,4): b = bx&7 pins batch to XCD.
__global__ __launch_bounds__(512) void conv_mfma(
    const unsigned short* __restrict__ xc, const unsigned short* __restrict__ wb3,
    const float* __restrict__ bo, float* __restrict__ out) {
  __shared__ unsigned short xlds[2][6656];    // 13 slots x 512 each buf
  __shared__ unsigned short wlds[2][27648];   // 54 slots x 512 each buf
  int tid = threadIdx.x;
  int lane = tid & 63; int il = lane & 15, q = lane >> 4;
  int wv = tid >> 6; int mh = wv >> 1, nh = wv & 1;
  int bx = blockIdx.x, nset = blockIdx.y;
  int b = bx & 7, pt = bx >> 3;             // pt 0..7; b fastest => XCD-pinned
  int pos0 = pt * 128, y0 = pt * 4;
  const unsigned short* xb = xc + ((size_t)(b * 8) * 1156 + y0 * 34) * 32;

  v4f acc[2][3];
#pragma unroll
  for (int mi = 0; mi < 2; ++mi)
#pragma unroll
    for (int j = 0; j < 3; ++j) acc[mi][j] = (v4f){0.f, 0.f, 0.f, 0.f};

  // X: lds chunk c=(row*4+q)*34+x <- global chunk row*136+x*4+q of slice kc.
  auto stageX = [&](int buf, int kc) {
    const unsigned short* src = xb + (size_t)kc * 36992;   // 1156*32
#pragma unroll
    for (int t = 0; t < 2; ++t) {
      int s = wv + t * 8;                   // wave-uniform slot
      if (s < 13) {
        int c = s * 64 + lane;
        int row = c / 136, rem = c % 136;
        int qv = rem / 34, xx = rem % 34;
        const unsigned short* g = src + ((row * 136 + xx * 4 + qv) << 3);
        __builtin_amdgcn_global_load_lds(
            (const __attribute__((address_space(1))) void*)g,
            (__attribute__((address_space(3))) void*)(&xlds[buf][s * 512]),
            16, 0, 0);
      }
    }
  };

  // W: lds [nfg][tap][512] <- WB3[(nset*6+nfg)][kc][tap]; slot s: nfg=s/9,tap=s%9.
  auto stageW = [&](int buf, int kc) {
#pragma unroll
    for (int t = 0; t < 7; ++t) {
      int s = wv + t * 8;                   // wave-uniform slot
      if (s < 54) {
        int nfg = s / 9, tp = s % 9;
        const unsigned short* g = wb3 +
            ((size_t)(((nset * 6 + nfg) * 8 + kc) * 9 + tp) * 512 + lane * 8);
        __builtin_amdgcn_global_load_lds(
            (const __attribute__((address_space(1))) void*)g,
            (__attribute__((address_space(3))) void*)(&wlds[buf][s * 512]),
            16, 0, 0);
      }
    }
  };

  stageX(0, 0);
  stageW(0, 0);
  __syncthreads();

  for (int kc = 0; kc < 8; ++kc) {
    int cur = kc & 1;
    if (kc < 7) {                           // async prefetch of kc+1
      stageX(cur ^ 1, kc + 1);
      stageW(cur ^ 1, kc + 1);
    }
#pragma unroll
    for (int tap = 0; tap < 9; ++tap) {
      int ky = tap / 3, kx = tap % 3;
      v8s af[2], bf[3];
#pragma unroll
      for (int j = 0; j < 3; ++j)
        bf[j] = *(const v8s*)&wlds[cur][((nh * 3 + j) * 9 + tap) * 512 + lane * 8];
#pragma unroll
      for (int mi = 0; mi < 2; ++mi) {
        int mf = mh * 2 + mi;
        af[mi] = *(const v8s*)&xlds[cur][((((mf >> 1) + ky) * 4 + q) * 34 +
                                          ((mf & 1) * 16 + kx + il)) * 8];
      }
#pragma unroll
      for (int mi = 0; mi < 2; ++mi)
#pragma unroll
        for (int j = 0; j < 3; ++j)
          acc[mi][j] = __builtin_amdgcn_mfma_f32_16x16x32_bf16(
              af[mi], bf[j], acc[mi][j], 0, 0, 0);
    }
    __syncthreads();   // all reads of cur done + prefetch into cur^1 drained
  }

  int co0 = nset * 96;
#pragma unroll
  for (int j = 0; j < 3; ++j) {
    int co = co0 + (nh * 3 + j) * 16 + il;
    float bias = bo[co];
#pragma unroll
    for (int mi = 0; mi < 2; ++mi) {
      int mf = mh * 2 + mi;
      v4f a = acc[mi][j];
      float4 v; v.x = a[0] + bias; v.y = a[1] + bias;
      v.z = a[2] + bias; v.w = a[3] + bias;
      *(float4*)(out + ((size_t)(b * 512 + co)) * 1024 +
                 pos0 + mf * 16 + q * 4) = v;
    }
  }
}

// ---------------------------------------------------------------------------
extern "C" void kernel_launch(void* const* d_in, const int* in_sizes, int n_in,
                              void* d_out, int out_size, void* d_ws, size_t ws_size,
                              hipStream_t stream) {
  const float* x      = (const float*)d_in[0];
  const float* b_out  = (const float*)d_in[2];
  const float* b_kqv  = (const float*)d_in[4];
  const float* b_attn = (const float*)d_in[6];
  const float* krw    = (const float*)d_in[7];
  const float* krh    = (const float*)d_in[8];
  unsigned short* ws = (unsigned short*)d_ws;
  float* out = (float*)d_out;
  unsigned short* dq = (unsigned short*)d_out;

  prep_kernel<<<1292, 256, 0, stream>>>(
      (const float*)d_in[1], (const float*)d_in[3], (const float*)d_in[5],
      krw, krh, x, ws);
  kqv_mfma<<<768, 256, 0, stream>>>(
      ws + XC_US, ws + WK2_US, b_kqv, dq);
  attn_mfma<<<dim3(64, 16), 256, 0, stream>>>(
      dq, ws + KRWB_US, ws + KRHB_US, ws + ART2_US);
  attn_out_mfma<<<256, 256, 0, stream>>>(
      dq, ws + ART2_US, ws + WA2_US, b_attn, out);
  conv_mfma<<<dim3(64, 4), 512, 0, stream>>>(
      ws + XC_US, ws + WB2_US, b_out, out);
}